// Round 3
// baseline (6314.626 us; speedup 1.0000x reference)
//
#include <hip/hip_runtime.h>
#include <hip/hip_cooperative_groups.h>

namespace cg = cooperative_groups;

typedef __attribute__((ext_vector_type(8))) short short8;
typedef __attribute__((ext_vector_type(4))) float f32x4;
typedef unsigned short ushort_t;

#define T_DIM 64
#define N_DIM 4096
#define DL 300
#define DA 74
#define DV 35
#define DTOT 409
#define ZD 256
#define GD 1024
#define FD 128
#define KP1_L 320
#define KP1_A 96
#define KP1_V 64
#define KT_L (KP1_L + 256)   // 576
#define KT_A (KP1_A + 256)   // 352
#define KT_V (KP1_V + 256)   // 320

__device__ __forceinline__ ushort_t f2bf(float v) {
    unsigned u = __float_as_uint(v);
    u += 0x7fffu + ((u >> 16) & 1u);
    return (ushort_t)(u >> 16);
}

// ---------------------------------------------------------------------------
// Weight conversion: Wc[m] = [W_ih | pad0 | W_hh] per output row, bf16
// ---------------------------------------------------------------------------
struct WConvP {
    const float* Wih[3];
    const float* Whh[3];
    ushort_t* wc[3];
    int d[3];
    int kp1[3];
    int kt[3];
};
__global__ __launch_bounds__(256) void wconv_kernel(WConvP p) {
    unsigned e = blockIdx.x * 256u + threadIdx.x;
    const unsigned n0 = 1024u * KT_L, n1 = n0 + 1024u * KT_A, n2 = n1 + 1024u * KT_V;
    int m;
    unsigned rel;
    if (e < n0) { m = 0; rel = e; }
    else if (e < n1) { m = 1; rel = e - n0; }
    else if (e < n2) { m = 2; rel = e - n1; }
    else return;
    int kt = p.kt[m];
    unsigned row = rel / (unsigned)kt;
    unsigned k = rel - row * (unsigned)kt;
    float v = 0.f;
    if ((int)k < p.d[m]) v = p.Wih[m][(size_t)row * p.d[m] + k];
    else if ((int)k >= p.kp1[m]) v = p.Whh[m][(size_t)row * 256u + (k - p.kp1[m])];
    p.wc[m][(size_t)row * kt + k] = f2bf(v);
}

// ---------------------------------------------------------------------------
// x conversion: padded bf16 slices, nt timesteps from t0
// ---------------------------------------------------------------------------
struct XConvP {
    const float* x;
    ushort_t* xb[3];
    int t0;
};
__global__ __launch_bounds__(256) void xconv_kernel(XConvP p) {
    unsigned e = blockIdx.x * 256u + threadIdx.x;
    unsigned row = e / 480u;
    unsigned k480 = e - row * 480u;
    int m, dm, off;
    unsigned k, kp1;
    if (k480 < 320u)      { m = 0; k = k480;        kp1 = KP1_L; dm = DL; off = 0; }
    else if (k480 < 416u) { m = 1; k = k480 - 320u; kp1 = KP1_A; dm = DA; off = DL; }
    else                  { m = 2; k = k480 - 416u; kp1 = KP1_V; dm = DV; off = DL + DA; }
    float v = 0.f;
    if ((int)k < dm) v = p.x[((size_t)p.t0 * N_DIM + row) * DTOT + off + k];
    ushort_t* xb = (m == 0) ? p.xb[0] : (m == 1) ? p.xb[1] : p.xb[2];
    xb[(size_t)row * kp1 + k] = f2bf(v);
}

// ---------------------------------------------------------------------------
// Persistent cooperative LSTM: whole T loop in one kernel.
// 384 blocks x 256 threads. Block = (m, 256-row tile, 32-z tile, 4 gates).
// c lives in registers for all 64 steps. h double-buffered in global.
// bid -> XCD mapping keeps the 8 col-blocks of a row-group on one XCD.
// ---------------------------------------------------------------------------
struct PersistP {
    const ushort_t* xb[3];   // [T][N][kp1]
    const ushort_t* wc[3];   // [1024][kt]
    const float* bih[3];
    const float* bhh[3];
    ushort_t* h0;            // [3][N][256]
    ushort_t* h1;
};

template <int KP1>
__device__ __forceinline__ void lstm_persist_body(const PersistP& p, int m, int r, int cb) {
    constexpr int KT = KP1 + 256;
    const int tid = threadIdx.x;
    const int w = tid >> 6, lane = tid & 63, ln = lane & 15, lg = lane >> 4;
    const int row0 = r * 256 + w * 64;
    const int z0 = cb * 32;

    const ushort_t* __restrict__ xb = p.xb[m];
    const ushort_t* __restrict__ wc = p.wc[m];
    ushort_t* h0 = p.h0 + (size_t)m * N_DIM * ZD;
    ushort_t* h1 = p.h1 + (size_t)m * N_DIM * ZD;

    const ushort_t* wptr[8];
#pragma unroll
    for (int cf = 0; cf < 8; ++cf) {
        int gate = cf >> 1, zh = cf & 1;
        wptr[cf] = wc + (size_t)(gate * ZD + z0 + zh * 16 + ln) * KT + lg * 8;
    }
    float bi[2], bff[2], bgg[2], boo[2];
#pragma unroll
    for (int zh = 0; zh < 2; ++zh) {
        int z = z0 + zh * 16 + ln;
        bi[zh]  = p.bih[m][z] + p.bhh[m][z];
        bff[zh] = p.bih[m][ZD + z] + p.bhh[m][ZD + z];
        bgg[zh] = p.bih[m][2 * ZD + z] + p.bhh[m][2 * ZD + z];
        boo[zh] = p.bih[m][3 * ZD + z] + p.bhh[m][3 * ZD + z];
    }
    size_t xoff[4], hoff[4];
#pragma unroll
    for (int rf = 0; rf < 4; ++rf) {
        xoff[rf] = (size_t)(row0 + rf * 16 + ln) * KP1 + lg * 8;
        hoff[rf] = (size_t)(row0 + rf * 16 + ln) * ZD + lg * 8;
    }

    float creg[4][2][4] = {};
    cg::grid_group grid = cg::this_grid();

    const ushort_t* hc = h0;
    ushort_t* hn = h1;
#pragma unroll 1
    for (int t = 0; t < T_DIM; ++t) {
        f32x4 acc[4][8] = {};
        const ushort_t* xbase = xb + (size_t)t * N_DIM * KP1;
#pragma unroll 1
        for (int k0 = 0; k0 < KP1; k0 += 32) {
            short8 a[4];
#pragma unroll
            for (int rf = 0; rf < 4; ++rf)
                a[rf] = *reinterpret_cast<const short8*>(xbase + xoff[rf] + k0);
#pragma unroll
            for (int cf = 0; cf < 8; ++cf) {
                short8 b = *reinterpret_cast<const short8*>(wptr[cf] + k0);
#pragma unroll
                for (int rf = 0; rf < 4; ++rf)
                    acc[rf][cf] = __builtin_amdgcn_mfma_f32_16x16x32_bf16(
                        a[rf], b, acc[rf][cf], 0, 0, 0);
            }
        }
#pragma unroll 1
        for (int k0 = 0; k0 < ZD; k0 += 32) {
            short8 a[4];
#pragma unroll
            for (int rf = 0; rf < 4; ++rf)
                a[rf] = *reinterpret_cast<const short8*>(hc + hoff[rf] + k0);
#pragma unroll
            for (int cf = 0; cf < 8; ++cf) {
                short8 b = *reinterpret_cast<const short8*>(wptr[cf] + KP1 + k0);
#pragma unroll
                for (int rf = 0; rf < 4; ++rf)
                    acc[rf][cf] = __builtin_amdgcn_mfma_f32_16x16x32_bf16(
                        a[rf], b, acc[rf][cf], 0, 0, 0);
            }
        }
        // pointwise + h write
#pragma unroll
        for (int rf = 0; rf < 4; ++rf) {
#pragma unroll
            for (int zh = 0; zh < 2; ++zh) {
#pragma unroll
                for (int reg = 0; reg < 4; ++reg) {
                    float gi = acc[rf][0 + zh][reg] + bi[zh];
                    float gf = acc[rf][2 + zh][reg] + bff[zh];
                    float gg = acc[rf][4 + zh][reg] + bgg[zh];
                    float go = acc[rf][6 + zh][reg] + boo[zh];
                    float i_ = 1.f / (1.f + __expf(-gi));
                    float f_ = 1.f / (1.f + __expf(-gf));
                    float g_ = 1.f - 2.f / (1.f + __expf(2.f * gg));
                    float o_ = 1.f / (1.f + __expf(-go));
                    float cc = f_ * creg[rf][zh][reg] + i_ * g_;
                    creg[rf][zh][reg] = cc;
                    float hh = o_ * (1.f - 2.f / (1.f + __expf(2.f * cc)));
                    int n = row0 + rf * 16 + lg * 4 + reg;
                    hn[(size_t)n * ZD + z0 + zh * 16 + ln] = f2bf(hh);
                }
            }
        }
        grid.sync();
        const ushort_t* tmp = hn;
        hn = (ushort_t*)hc;
        hc = tmp;
    }
}

__global__ __launch_bounds__(256, 2) void lstm_persist_kernel(PersistP p) {
    const int bid = blockIdx.x;
    const int xcd = bid & 7;
    const int rest = bid >> 3;
    const int cb = rest & 7;
    const int gg = rest >> 3;
    const int g = gg * 8 + xcd;   // 0..47
    const int m = g >> 4;
    const int r = g & 15;
    if (m == 0)      lstm_persist_body<KP1_L>(p, 0, r, cb);
    else if (m == 1) lstm_persist_body<KP1_A>(p, 1, r, cb);
    else             lstm_persist_body<KP1_V>(p, 2, r, cb);
}

// ---------------------------------------------------------------------------
// Fallback per-step kernel (race-free: separate h_in / h_out)
// ---------------------------------------------------------------------------
struct StepP {
    const ushort_t* xb[3];
    const ushort_t* wc[3];
    const float* bih[3];
    const float* bhh[3];
    const ushort_t* h_in;
    ushort_t* h_out;
    float* c;
    int kp1[3];
    int kt[3];
};
__global__ __launch_bounds__(256) void lstm_step_kernel(StepP p) {
    const int m = blockIdx.z;
    const ushort_t* __restrict__ xb = p.xb[m];
    const ushort_t* __restrict__ wc = p.wc[m];
    const int kp1 = p.kp1[m], kt = p.kt[m];
    const ushort_t* __restrict__ hin = p.h_in + (size_t)m * N_DIM * ZD;
    ushort_t* __restrict__ hout = p.h_out + (size_t)m * N_DIM * ZD;
    float* __restrict__ c = p.c + (size_t)m * N_DIM * ZD;
    const int row0 = blockIdx.x * 64, z0 = blockIdx.y * 64;
    const int tid = threadIdx.x, w = tid >> 6;
    const int lane = tid & 63, ln = lane & 15, lg = lane >> 4;

    f32x4 acc[4][4] = {};
    const ushort_t* wrow[4];
#pragma unroll
    for (int cf = 0; cf < 4; ++cf)
        wrow[cf] = wc + (size_t)(cf * ZD + z0 + w * 16 + ln) * kt + lg * 8;

    for (int k0 = 0; k0 < kt; k0 += 32) {
        short8 a[4], b[4];
        if (k0 < kp1) {
#pragma unroll
            for (int rf = 0; rf < 4; ++rf)
                a[rf] = *reinterpret_cast<const short8*>(
                    xb + (size_t)(row0 + rf * 16 + ln) * kp1 + k0 + lg * 8);
        } else {
#pragma unroll
            for (int rf = 0; rf < 4; ++rf)
                a[rf] = *reinterpret_cast<const short8*>(
                    hin + (size_t)(row0 + rf * 16 + ln) * ZD + (k0 - kp1) + lg * 8);
        }
#pragma unroll
        for (int cf = 0; cf < 4; ++cf)
            b[cf] = *reinterpret_cast<const short8*>(wrow[cf] + k0);
#pragma unroll
        for (int rf = 0; rf < 4; ++rf)
#pragma unroll
            for (int cf = 0; cf < 4; ++cf)
                acc[rf][cf] = __builtin_amdgcn_mfma_f32_16x16x32_bf16(
                    a[rf], b[cf], acc[rf][cf], 0, 0, 0);
    }

    const int z = z0 + w * 16 + ln;
    const float* __restrict__ bih = p.bih[m];
    const float* __restrict__ bhh = p.bhh[m];
    const float bi = bih[z] + bhh[z];
    const float bf_ = bih[ZD + z] + bhh[ZD + z];
    const float bg = bih[2 * ZD + z] + bhh[2 * ZD + z];
    const float bo = bih[3 * ZD + z] + bhh[3 * ZD + z];
#pragma unroll
    for (int rf = 0; rf < 4; ++rf) {
#pragma unroll
        for (int reg = 0; reg < 4; ++reg) {
            const int n = row0 + rf * 16 + lg * 4 + reg;
            const size_t idx = (size_t)n * ZD + z;
            float gi = acc[rf][0][reg] + bi;
            float gf = acc[rf][1][reg] + bf_;
            float gg = acc[rf][2][reg] + bg;
            float go = acc[rf][3][reg] + bo;
            float i_ = 1.f / (1.f + __expf(-gi));
            float f_ = 1.f / (1.f + __expf(-gf));
            float g_ = 1.f - 2.f / (1.f + __expf(2.f * gg));
            float o_ = 1.f / (1.f + __expf(-go));
            float cc = f_ * c[idx] + i_ * g_;
            c[idx] = cc;
            float hh = o_ * (1.f - 2.f / (1.f + __expf(2.f * cc)));
            hout[idx] = f2bf(hh);
        }
    }
}

// ---------------------------------------------------------------------------
// h bf16 -> f32
// ---------------------------------------------------------------------------
__global__ __launch_bounds__(256) void h2f_kernel(const ushort_t* __restrict__ h,
                                                  float* __restrict__ hf) {
    unsigned i = blockIdx.x * 256u + threadIdx.x;
    hf[i] = __uint_as_float(((unsigned)h[i]) << 16);
}

// ---------------------------------------------------------------------------
// fp32 tiled GEMM for the small head layers
// ---------------------------------------------------------------------------
struct GemmP {
    const float* A1[3];
    const float* W1[3];
    const float* b1[3];
    float* C[3];
    int K1[3];
    int lda1;
    int ldc;
    int relu;
};

__device__ __forceinline__ void mac16(const float (&As)[16][64], const float (&Ws)[16][64],
                                      int tx, int ty, float (&acc)[4][4]) {
#pragma unroll
    for (int k = 0; k < 16; ++k) {
        float4 av = *reinterpret_cast<const float4*>(&As[k][ty * 4]);
        float4 bv = *reinterpret_cast<const float4*>(&Ws[k][tx * 4]);
        float a[4] = {av.x, av.y, av.z, av.w};
        float b[4] = {bv.x, bv.y, bv.z, bv.w};
#pragma unroll
        for (int i = 0; i < 4; ++i)
#pragma unroll
            for (int j = 0; j < 4; ++j)
                acc[i][j] = fmaf(a[i], b[j], acc[i][j]);
    }
}

__global__ __launch_bounds__(256) void gemm3_kernel(GemmP p) {
    const int m = blockIdx.z;
    const float* __restrict__ A1 = p.A1[m];
    const float* __restrict__ W1 = p.W1[m];
    const int K1 = p.K1[m];
    float* __restrict__ C = p.C[m];
    const int row0 = blockIdx.x * 64;
    const int col0 = blockIdx.y * 64;

    __shared__ __align__(16) float As[16][64];
    __shared__ __align__(16) float Ws[16][64];

    const int tid = threadIdx.x;
    const int tx = tid & 15, ty = tid >> 4;
    float acc[4][4] = {};

    for (int k0 = 0; k0 < K1; k0 += 16) {
#pragma unroll
        for (int i = 0; i < 4; ++i) {
            int e = tid * 4 + i;
            int r = e >> 4, k = e & 15;
            int kk = k0 + k;
            As[k][r] = (kk < K1) ? A1[(size_t)(row0 + r) * p.lda1 + kk] : 0.f;
            Ws[k][r] = (kk < K1) ? W1[(size_t)(col0 + r) * K1 + kk] : 0.f;
        }
        __syncthreads();
        mac16(As, Ws, tx, ty, acc);
        __syncthreads();
    }

    const float* __restrict__ b1 = p.b1[m];
#pragma unroll
    for (int i = 0; i < 4; ++i) {
        int r = row0 + ty * 4 + i;
        float v[4];
#pragma unroll
        for (int j = 0; j < 4; ++j) {
            int cc = col0 + tx * 4 + j;
            float t = acc[i][j] + b1[cc];
            if (p.relu) t = fmaxf(t, 0.f);
            v[j] = t;
        }
        float4 o = make_float4(v[0], v[1], v[2], v[3]);
        *reinterpret_cast<float4*>(&C[(size_t)r * p.ldc + col0 + tx * 4]) = o;
    }
}

// ---------------------------------------------------------------------------
// split x into the three output slices
// ---------------------------------------------------------------------------
__global__ __launch_bounds__(256) void split_kernel(const float* __restrict__ x,
                                                    float* __restrict__ out_l,
                                                    float* __restrict__ out_a,
                                                    float* __restrict__ out_v) {
    const unsigned total = (unsigned)T_DIM * N_DIM * DTOT;
    unsigned stride = gridDim.x * 256u;
    for (unsigned s = blockIdx.x * 256u + threadIdx.x; s < total; s += stride) {
        unsigned row = s / DTOT;
        unsigned d = s - row * DTOT;
        float v = x[s];
        if (d < DL)            out_l[(size_t)row * DL + d] = v;
        else if (d < DL + DA)  out_a[(size_t)row * DA + (d - DL)] = v;
        else                   out_v[(size_t)row * DV + (d - DL - DA)] = v;
    }
}

// ---------------------------------------------------------------------------
// y[n] = dot(fs[n,:384], Wy) + by
// ---------------------------------------------------------------------------
__global__ __launch_bounds__(256) void y_kernel(const float* __restrict__ fs,
                                                const float* __restrict__ Wy,
                                                const float* __restrict__ by,
                                                float* __restrict__ y) {
    unsigned wave = (blockIdx.x * 256u + threadIdx.x) >> 6;
    unsigned lane = threadIdx.x & 63u;
    if (wave >= N_DIM) return;
    const float* row = fs + (size_t)wave * 3 * FD;
    float s = 0.f;
    for (unsigned j = lane; j < 3 * FD; j += 64) s += row[j] * Wy[j];
#pragma unroll
    for (int off = 32; off; off >>= 1) s += __shfl_down(s, off);
    if (lane == 0) y[wave] = s + by[0];
}

extern "C" void kernel_launch(void* const* d_in, const int* in_sizes, int n_in,
                              void* d_out, int out_size, void* d_ws, size_t ws_size,
                              hipStream_t stream) {
    const float* x = (const float*)d_in[0];
    const float *W_ih[3], *W_hh[3], *b_ih[3], *b_hh[3], *Wfc[3], *bfc[3],
                *Wh1[3], *bh1[3], *Wh2[3], *bh2[3];
    for (int m = 0; m < 3; ++m) {
        const int b = 1 + m * 10;
        W_ih[m] = (const float*)d_in[b + 0];
        W_hh[m] = (const float*)d_in[b + 1];
        b_ih[m] = (const float*)d_in[b + 2];
        b_hh[m] = (const float*)d_in[b + 3];
        Wfc[m]  = (const float*)d_in[b + 4];
        bfc[m]  = (const float*)d_in[b + 5];
        Wh1[m]  = (const float*)d_in[b + 6];
        bh1[m]  = (const float*)d_in[b + 7];
        Wh2[m]  = (const float*)d_in[b + 8];
        bh2[m]  = (const float*)d_in[b + 9];
    }
    const float* Wy = (const float*)d_in[31];
    const float* by = (const float*)d_in[32];

    float* out   = (float*)d_out;
    float* out_l = out;
    float* out_a = out_l + (size_t)T_DIM * N_DIM * DL;
    float* out_v = out_a + (size_t)T_DIM * N_DIM * DA;
    float* out_y = out_v + (size_t)T_DIM * N_DIM * DV;

    const size_t NZ = (size_t)N_DIM * ZD;
    const size_t NF = (size_t)N_DIM * FD;

    // workspace layout
    char* wsb = (char*)d_ws;
    ushort_t* h0   = (ushort_t*)wsb;                                   // 3NZ bf16
    ushort_t* h1   = h0 + 3 * NZ;                                      // 3NZ bf16
    ushort_t* wc_l = h1 + 3 * NZ;                                      // weights
    ushort_t* wc_a = wc_l + (size_t)1024 * KT_L;
    ushort_t* wc_v = wc_a + (size_t)1024 * KT_A;
    float* hf   = (float*)(wc_v + (size_t)1024 * KT_V);                // 3NZ f32
    float* zbuf = hf + 3 * NZ;
    float* f1   = zbuf + 3 * NZ;
    float* fs   = f1 + 3 * NF;
    char*  xb0  = (char*)(fs + 3 * NF);
    float* cbuf = hf;  // fallback-only c storage; aliases hf (dead during loop)

    const size_t fixed = (size_t)(xb0 - wsb);
    const size_t xb_small = (size_t)N_DIM * (KP1_L + KP1_A + KP1_V) * 2;
    const size_t xb_big   = xb_small * T_DIM;
    if (ws_size < fixed + xb_small) return;
    const bool big = (ws_size >= fixed + xb_big);
    const int ntcap = big ? T_DIM : 1;

    ushort_t* xb_l = (ushort_t*)xb0;
    ushort_t* xb_a = xb_l + (size_t)ntcap * N_DIM * KP1_L;
    ushort_t* xb_v = xb_a + (size_t)ntcap * N_DIM * KP1_A;

    // zero initial h (buffer 0)
    hipMemsetAsync(h0, 0, 3 * NZ * sizeof(ushort_t), stream);

    // weight conversion
    {
        WConvP p{};
        for (int m = 0; m < 3; ++m) { p.Wih[m] = W_ih[m]; p.Whh[m] = W_hh[m]; }
        p.wc[0] = wc_l; p.wc[1] = wc_a; p.wc[2] = wc_v;
        p.d[0] = DL; p.d[1] = DA; p.d[2] = DV;
        p.kp1[0] = KP1_L; p.kp1[1] = KP1_A; p.kp1[2] = KP1_V;
        p.kt[0] = KT_L; p.kt[1] = KT_A; p.kt[2] = KT_V;
        wconv_kernel<<<(1024 * (KT_L + KT_A + KT_V)) / 256, 256, 0, stream>>>(p);
    }

    // output slice copies
    split_kernel<<<4096, 256, 0, stream>>>(x, out_l, out_a, out_v);

    // x conversion (all steps when workspace allows)
    if (big) {
        XConvP p{};
        p.x = x; p.xb[0] = xb_l; p.xb[1] = xb_a; p.xb[2] = xb_v; p.t0 = 0;
        xconv_kernel<<<(T_DIM * N_DIM * 480) / 256, 256, 0, stream>>>(p);
    }

    // ---- LSTM: persistent cooperative kernel, fallback to per-step ----
    bool coop_done = false;
    if (big) {
        PersistP pp{};
        pp.xb[0] = xb_l; pp.xb[1] = xb_a; pp.xb[2] = xb_v;
        pp.wc[0] = wc_l; pp.wc[1] = wc_a; pp.wc[2] = wc_v;
        for (int m = 0; m < 3; ++m) { pp.bih[m] = b_ih[m]; pp.bhh[m] = b_hh[m]; }
        pp.h0 = h0; pp.h1 = h1;
        void* args[] = {&pp};
        hipError_t ce = hipLaunchCooperativeKernel((void*)lstm_persist_kernel,
                                                   dim3(384), dim3(256), args, 0, stream);
        coop_done = (ce == hipSuccess);
    }
    if (!coop_done) {
        // race-free per-step fallback (double-buffered h, c in cbuf)
        hipMemsetAsync(cbuf, 0, 3 * NZ * sizeof(float), stream);
        StepP sp{};
        sp.wc[0] = wc_l; sp.wc[1] = wc_a; sp.wc[2] = wc_v;
        for (int m = 0; m < 3; ++m) { sp.bih[m] = b_ih[m]; sp.bhh[m] = b_hh[m]; }
        sp.c = cbuf;
        sp.kp1[0] = KP1_L; sp.kp1[1] = KP1_A; sp.kp1[2] = KP1_V;
        sp.kt[0] = KT_L; sp.kt[1] = KT_A; sp.kt[2] = KT_V;
        for (int t = 0; t < T_DIM; ++t) {
            if (!big) {
                XConvP p{};
                p.x = x; p.xb[0] = xb_l; p.xb[1] = xb_a; p.xb[2] = xb_v; p.t0 = t;
                xconv_kernel<<<(N_DIM * 480) / 256, 256, 0, stream>>>(p);
            }
            const size_t ts = big ? (size_t)t : 0;
            sp.xb[0] = xb_l + ts * N_DIM * KP1_L;
            sp.xb[1] = xb_a + ts * N_DIM * KP1_A;
            sp.xb[2] = xb_v + ts * N_DIM * KP1_V;
            sp.h_in  = (t & 1) ? h1 : h0;
            sp.h_out = (t & 1) ? h0 : h1;
            lstm_step_kernel<<<dim3(N_DIM / 64, ZD / 64, 3), 256, 0, stream>>>(sp);
        }
    }

    // final h is in h0 (64 steps, even) -> f32
    h2f_kernel<<<(3 * NZ) / 256, 256, 0, stream>>>(h0, hf);

    // z = h @ Wfc^T + bfc
    {
        GemmP p{};
        for (int m = 0; m < 3; ++m) {
            p.A1[m] = hf + m * NZ; p.W1[m] = Wfc[m]; p.K1[m] = ZD;
            p.b1[m] = bfc[m];      p.C[m] = zbuf + m * NZ;
        }
        p.lda1 = ZD; p.ldc = ZD; p.relu = 0;
        gemm3_kernel<<<dim3(N_DIM / 64, ZD / 64, 3), 256, 0, stream>>>(p);
    }
    // f1 = relu(z @ Wh1^T + bh1)
    {
        GemmP p{};
        for (int m = 0; m < 3; ++m) {
            p.A1[m] = zbuf + m * NZ; p.W1[m] = Wh1[m]; p.K1[m] = ZD;
            p.b1[m] = bh1[m];        p.C[m] = f1 + m * NF;
        }
        p.lda1 = ZD; p.ldc = FD; p.relu = 1;
        gemm3_kernel<<<dim3(N_DIM / 64, FD / 64, 3), 256, 0, stream>>>(p);
    }
    // fs[:, m*128:(m+1)*128] = relu(f1 @ Wh2^T + bh2)
    {
        GemmP p{};
        for (int m = 0; m < 3; ++m) {
            p.A1[m] = f1 + m * NF; p.W1[m] = Wh2[m]; p.K1[m] = FD;
            p.b1[m] = bh2[m];      p.C[m] = fs + m * FD;
        }
        p.lda1 = FD; p.ldc = 3 * FD; p.relu = 1;
        gemm3_kernel<<<dim3(N_DIM / 64, FD / 64, 3), 256, 0, stream>>>(p);
    }
    // y
    y_kernel<<<(N_DIM * 64) / 256, 256, 0, stream>>>(fs, Wy, by, out_y);
}

// Round 4
// 3930.965 us; speedup vs baseline: 1.6064x; 1.6064x over previous
//
#include <hip/hip_runtime.h>
#include <hip/hip_cooperative_groups.h>

namespace cg = cooperative_groups;

typedef __attribute__((ext_vector_type(8))) short short8;
typedef __attribute__((ext_vector_type(4))) float f32x4;
typedef unsigned short ushort_t;

#define T_DIM 64
#define N_DIM 4096
#define DL 300
#define DA 74
#define DV 35
#define DTOT 409
#define ZD 256
#define FD 128

__device__ __forceinline__ ushort_t f2bf(float v) {
    unsigned u = __float_as_uint(v);
    u += 0x7fffu + ((u >> 16) & 1u);
    return (ushort_t)(u >> 16);
}

// ---------------------------------------------------------------------------
// x conversion into A-fragment layout:
//   xf[m] : [t][nb=n/16][kc][lane 64][8]   value = x[t][nb*16+(lane&15)][off + kc*32 + (lane>>4)*8 + j]
// Writes are 16B/thread, fully coalesced.
// ---------------------------------------------------------------------------
struct XConvP {
    const float* x;
    ushort_t* xf[3];
};
__global__ __launch_bounds__(256) void xconv_kernel(XConvP p) {
    const unsigned EL = 64u * 256u * 10u * 64u;   // 10,485,760
    const unsigned EA = 64u * 256u * 3u * 64u;    //  3,145,728
    const unsigned EV = 64u * 256u * 2u * 64u;    //  2,097,152
    unsigned e = blockIdx.x * 256u + threadIdx.x;
    unsigned rel;
    int xkc, dm, off;
    ushort_t* outp;
    if (e < EL)           { rel = e;           xkc = 10; dm = DL; off = 0;       outp = p.xf[0]; }
    else if (e < EL + EA) { rel = e - EL;      xkc = 3;  dm = DA; off = DL;      outp = p.xf[1]; }
    else if (e < EL + EA + EV) { rel = e - EL - EA; xkc = 2; dm = DV; off = DL + DA; outp = p.xf[2]; }
    else return;
    unsigned lane = rel & 63u;
    unsigned rest = rel >> 6;                 // (t*256+nb)*xkc + kc
    unsigned kc  = rest % (unsigned)xkc;
    unsigned tnb = rest / (unsigned)xkc;
    unsigned nb = tnb & 255u;
    unsigned t  = tnb >> 8;
    unsigned n  = nb * 16u + (lane & 15u);
    unsigned kb = kc * 32u + (lane >> 4) * 8u;
    const float* src = p.x + ((size_t)t * N_DIM + n) * DTOT + off;
    ushort_t tmp[8];
#pragma unroll
    for (int j = 0; j < 8; ++j) {
        int k = (int)kb + j;
        tmp[j] = (k < dm) ? f2bf(src[k]) : (ushort_t)0;
    }
    *reinterpret_cast<short8*>(&outp[(size_t)rel * 8]) = *reinterpret_cast<short8*>(tmp);
}

// ---------------------------------------------------------------------------
// Persistent cooperative LSTM. 256 blocks x 512 threads, 1 block/CU.
// Block = (m, 512-row n-tile r, z-slice cb). Weights staged to LDS once
// (bf16 B-fragment layout). c in registers. h double-buffered in global,
// exchanged per step via grid.sync().
// bid: r = bid&7 (XCD under %8 round-robin => all cb of a row-group co-XCD),
//      idx = bid>>3: [0,16) -> L(cb=idx), [16,24) -> A, [24,32) -> V.
// ---------------------------------------------------------------------------
struct PersistP {
    const ushort_t* xf[3];
    const float* Wih[3];
    const float* Whh[3];
    const float* bih[3];
    const float* bhh[3];
    ushort_t* h0;
    ushort_t* h1;
};

template <int KP1, int ZW, int D>
__device__ __forceinline__ void persist_body(const PersistP& p, int m, int r, int cb,
                                             ushort_t* wlds) {
    constexpr int KT = KP1 + 256;
    constexpr int KC = KT / 32;
    constexpr int XKC = KP1 / 32;
    constexpr int ZHC = ZW / 16;
    constexpr int NCF = 4 * ZHC;
    const int tid = threadIdx.x;
    const int w = tid >> 6, lane = tid & 63, ln = lane & 15, lg = lane >> 4;
    const int row0 = r * 512 + w * 64;
    const int z0 = cb * ZW;

    // ---- stage weights into LDS (fragment order), once ----
    {
        const float* __restrict__ Wih = p.Wih[m];
        const float* __restrict__ Whh = p.Whh[m];
        for (int e = tid; e < NCF * KC * 64; e += 512) {
            int l = e & 63;
            int rk = e >> 6;
            int kc = rk % KC, cf = rk / KC;
            int gate = cf / ZHC, zh = cf - gate * ZHC;
            int grow = gate * 256 + z0 + zh * 16 + (l & 15);
            int kb = kc * 32 + (l >> 4) * 8;
            ushort_t tmp[8];
#pragma unroll
            for (int j = 0; j < 8; ++j) {
                int k = kb + j;
                float v = 0.f;
                if (k < D) v = Wih[(size_t)grow * D + k];
                else if (k >= KP1) v = Whh[(size_t)grow * 256 + (k - KP1)];
                tmp[j] = f2bf(v);
            }
            *reinterpret_cast<short8*>(&wlds[e * 8]) = *reinterpret_cast<short8*>(tmp);
        }
    }
    __syncthreads();

    float bi[ZHC], bf_[ZHC], bg[ZHC], bo[ZHC];
#pragma unroll
    for (int zh = 0; zh < ZHC; ++zh) {
        int z = z0 + zh * 16 + ln;
        bi[zh]  = p.bih[m][z] + p.bhh[m][z];
        bf_[zh] = p.bih[m][256 + z] + p.bhh[m][256 + z];
        bg[zh]  = p.bih[m][512 + z] + p.bhh[m][512 + z];
        bo[zh]  = p.bih[m][768 + z] + p.bhh[m][768 + z];
    }

    const ushort_t* __restrict__ xf = p.xf[m];
    const ushort_t* hc = p.h0 + (size_t)m * N_DIM * ZD;
    ushort_t* hn = p.h1 + (size_t)m * N_DIM * ZD;
    const int nb0 = row0 >> 4;

    float creg[4][ZHC][4] = {};
    cg::grid_group grid = cg::this_grid();

#pragma unroll 1
    for (int t = 0; t < T_DIM; ++t) {
        f32x4 acc[4][NCF] = {};
        // x part: coalesced fragment loads
#pragma unroll 2
        for (int kc = 0; kc < XKC; ++kc) {
            short8 a[4];
#pragma unroll
            for (int rf = 0; rf < 4; ++rf)
                a[rf] = *reinterpret_cast<const short8*>(
                    xf + ((((size_t)t * 256 + nb0 + rf) * XKC + kc) * 64 + lane) * 8);
#pragma unroll
            for (int cf = 0; cf < NCF; ++cf) {
                short8 b = *reinterpret_cast<const short8*>(
                    &wlds[((cf * KC + kc) * 64 + lane) * 8]);
#pragma unroll
                for (int rf = 0; rf < 4; ++rf)
                    acc[rf][cf] = __builtin_amdgcn_mfma_f32_16x16x32_bf16(
                        a[rf], b, acc[rf][cf], 0, 0, 0);
            }
        }
        // h part
#pragma unroll 2
        for (int kc2 = 0; kc2 < 8; ++kc2) {
            short8 a[4];
#pragma unroll
            for (int rf = 0; rf < 4; ++rf)
                a[rf] = *reinterpret_cast<const short8*>(
                    hc + (size_t)(row0 + rf * 16 + ln) * ZD + kc2 * 32 + lg * 8);
#pragma unroll
            for (int cf = 0; cf < NCF; ++cf) {
                short8 b = *reinterpret_cast<const short8*>(
                    &wlds[((cf * KC + XKC + kc2) * 64 + lane) * 8]);
#pragma unroll
                for (int rf = 0; rf < 4; ++rf)
                    acc[rf][cf] = __builtin_amdgcn_mfma_f32_16x16x32_bf16(
                        a[rf], b, acc[rf][cf], 0, 0, 0);
            }
        }
        // pointwise epilogue, h write
#pragma unroll
        for (int rf = 0; rf < 4; ++rf)
#pragma unroll
            for (int zh = 0; zh < ZHC; ++zh)
#pragma unroll
                for (int reg = 0; reg < 4; ++reg) {
                    float gi = acc[rf][0 * ZHC + zh][reg] + bi[zh];
                    float gf = acc[rf][1 * ZHC + zh][reg] + bf_[zh];
                    float gg = acc[rf][2 * ZHC + zh][reg] + bg[zh];
                    float go = acc[rf][3 * ZHC + zh][reg] + bo[zh];
                    float i_ = 1.f / (1.f + __expf(-gi));
                    float f_ = 1.f / (1.f + __expf(-gf));
                    float g_ = 1.f - 2.f / (1.f + __expf(2.f * gg));
                    float o_ = 1.f / (1.f + __expf(-go));
                    float cc = f_ * creg[rf][zh][reg] + i_ * g_;
                    creg[rf][zh][reg] = cc;
                    float hh = o_ * (1.f - 2.f / (1.f + __expf(2.f * cc)));
                    int n = row0 + rf * 16 + lg * 4 + reg;
                    hn[(size_t)n * ZD + z0 + zh * 16 + ln] = f2bf(hh);
                }
        grid.sync();
        const ushort_t* tswap = hn;
        hn = (ushort_t*)hc;
        hc = tswap;
    }
}

__global__ __launch_bounds__(512, 2) void lstm_persist_kernel(PersistP p) {
    __shared__ ushort_t wlds[45056];   // 90112 B (max over modalities)
    const int bid = blockIdx.x;
    const int r = bid & 7;
    const int idx = bid >> 3;
    if (idx < 16)      persist_body<320, 16, DL>(p, 0, r, idx, wlds);
    else if (idx < 24) persist_body<96, 32, DA>(p, 1, r, idx - 16, wlds);
    else               persist_body<64, 32, DV>(p, 2, r, idx - 24, wlds);
}

// ---------------------------------------------------------------------------
// h bf16 -> f32
// ---------------------------------------------------------------------------
__global__ __launch_bounds__(256) void h2f_kernel(const ushort_t* __restrict__ h,
                                                  float* __restrict__ hf) {
    unsigned i = blockIdx.x * 256u + threadIdx.x;
    hf[i] = __uint_as_float(((unsigned)h[i]) << 16);
}

// ---------------------------------------------------------------------------
// fp32 tiled GEMM for the head layers
// ---------------------------------------------------------------------------
struct GemmP {
    const float* A1[3];
    const float* W1[3];
    const float* b1[3];
    float* C[3];
    int K1[3];
    int lda1;
    int ldc;
    int relu;
};

__device__ __forceinline__ void mac16(const float (&As)[16][64], const float (&Ws)[16][64],
                                      int tx, int ty, float (&acc)[4][4]) {
#pragma unroll
    for (int k = 0; k < 16; ++k) {
        float4 av = *reinterpret_cast<const float4*>(&As[k][ty * 4]);
        float4 bv = *reinterpret_cast<const float4*>(&Ws[k][tx * 4]);
        float a[4] = {av.x, av.y, av.z, av.w};
        float b[4] = {bv.x, bv.y, bv.z, bv.w};
#pragma unroll
        for (int i = 0; i < 4; ++i)
#pragma unroll
            for (int j = 0; j < 4; ++j)
                acc[i][j] = fmaf(a[i], b[j], acc[i][j]);
    }
}

__global__ __launch_bounds__(256) void gemm3_kernel(GemmP p) {
    const int m = blockIdx.z;
    const float* __restrict__ A1 = p.A1[m];
    const float* __restrict__ W1 = p.W1[m];
    const int K1 = p.K1[m];
    float* __restrict__ C = p.C[m];
    const int row0 = blockIdx.x * 64;
    const int col0 = blockIdx.y * 64;

    __shared__ __align__(16) float As[16][64];
    __shared__ __align__(16) float Ws[16][64];

    const int tid = threadIdx.x;
    const int tx = tid & 15, ty = tid >> 4;
    float acc[4][4] = {};

    for (int k0 = 0; k0 < K1; k0 += 16) {
#pragma unroll
        for (int i = 0; i < 4; ++i) {
            int e = tid * 4 + i;
            int rr = e >> 4, k = e & 15;
            int kk = k0 + k;
            As[k][rr] = (kk < K1) ? A1[(size_t)(row0 + rr) * p.lda1 + kk] : 0.f;
            Ws[k][rr] = (kk < K1) ? W1[(size_t)(col0 + rr) * K1 + kk] : 0.f;
        }
        __syncthreads();
        mac16(As, Ws, tx, ty, acc);
        __syncthreads();
    }

    const float* __restrict__ b1 = p.b1[m];
#pragma unroll
    for (int i = 0; i < 4; ++i) {
        int rr = row0 + ty * 4 + i;
        float v[4];
#pragma unroll
        for (int j = 0; j < 4; ++j) {
            int cc = col0 + tx * 4 + j;
            float tvl = acc[i][j] + b1[cc];
            if (p.relu) tvl = fmaxf(tvl, 0.f);
            v[j] = tvl;
        }
        float4 o = make_float4(v[0], v[1], v[2], v[3]);
        *reinterpret_cast<float4*>(&C[(size_t)rr * p.ldc + col0 + tx * 4]) = o;
    }
}

// ---------------------------------------------------------------------------
// split x into slice outputs — output-major indexing (both sides coalesced)
// ---------------------------------------------------------------------------
__global__ __launch_bounds__(256) void split_kernel(const float* __restrict__ x,
                                                    float* __restrict__ ol,
                                                    float* __restrict__ oa,
                                                    float* __restrict__ ov) {
    const unsigned TN = (unsigned)T_DIM * N_DIM;       // 262144
    const unsigned SL = TN * (unsigned)DL;             // 78,643,200
    const unsigned SA = TN * (unsigned)DA;             // 19,398,656
    const unsigned SV = TN * (unsigned)DV;             //  9,175,040
    const unsigned TOT = SL + SA + SV;
    unsigned stride = gridDim.x * 256u;
    for (unsigned s = blockIdx.x * 256u + threadIdx.x; s < TOT; s += stride) {
        if (s < SL) {
            unsigned row = s / (unsigned)DL, d = s - row * (unsigned)DL;
            ol[s] = x[(size_t)row * DTOT + d];
        } else if (s < SL + SA) {
            unsigned q = s - SL;
            unsigned row = q / (unsigned)DA, d = q - row * (unsigned)DA;
            oa[q] = x[(size_t)row * DTOT + DL + d];
        } else {
            unsigned q = s - SL - SA;
            unsigned row = q / (unsigned)DV, d = q - row * (unsigned)DV;
            ov[q] = x[(size_t)row * DTOT + DL + DA + d];
        }
    }
}

// ---------------------------------------------------------------------------
// y[n] = dot(fs[n,:384], Wy) + by
// ---------------------------------------------------------------------------
__global__ __launch_bounds__(256) void y_kernel(const float* __restrict__ fs,
                                                const float* __restrict__ Wy,
                                                const float* __restrict__ by,
                                                float* __restrict__ y) {
    unsigned wave = (blockIdx.x * 256u + threadIdx.x) >> 6;
    unsigned lane = threadIdx.x & 63u;
    if (wave >= N_DIM) return;
    const float* row = fs + (size_t)wave * 3 * FD;
    float s = 0.f;
    for (unsigned j = lane; j < 3 * FD; j += 64) s += row[j] * Wy[j];
#pragma unroll
    for (int off = 32; off; off >>= 1) s += __shfl_down(s, off);
    if (lane == 0) y[wave] = s + by[0];
}

extern "C" void kernel_launch(void* const* d_in, const int* in_sizes, int n_in,
                              void* d_out, int out_size, void* d_ws, size_t ws_size,
                              hipStream_t stream) {
    const float* x = (const float*)d_in[0];
    const float *W_ih[3], *W_hh[3], *b_ih[3], *b_hh[3], *Wfc[3], *bfc[3],
                *Wh1[3], *bh1[3], *Wh2[3], *bh2[3];
    for (int m = 0; m < 3; ++m) {
        const int b = 1 + m * 10;
        W_ih[m] = (const float*)d_in[b + 0];
        W_hh[m] = (const float*)d_in[b + 1];
        b_ih[m] = (const float*)d_in[b + 2];
        b_hh[m] = (const float*)d_in[b + 3];
        Wfc[m]  = (const float*)d_in[b + 4];
        bfc[m]  = (const float*)d_in[b + 5];
        Wh1[m]  = (const float*)d_in[b + 6];
        bh1[m]  = (const float*)d_in[b + 7];
        Wh2[m]  = (const float*)d_in[b + 8];
        bh2[m]  = (const float*)d_in[b + 9];
    }
    const float* Wy = (const float*)d_in[31];
    const float* by = (const float*)d_in[32];

    float* out   = (float*)d_out;
    float* out_l = out;
    float* out_a = out_l + (size_t)T_DIM * N_DIM * DL;
    float* out_v = out_a + (size_t)T_DIM * N_DIM * DA;
    float* out_y = out_v + (size_t)T_DIM * N_DIM * DV;

    const size_t NZ = (size_t)N_DIM * ZD;
    const size_t NF = (size_t)N_DIM * FD;

    // workspace layout
    char* wsb = (char*)d_ws;
    ushort_t* h0 = (ushort_t*)wsb;                       // 3NZ bf16
    ushort_t* h1 = h0 + 3 * NZ;                          // 3NZ bf16
    float* hf   = (float*)(h1 + 3 * NZ);                 // 3NZ f32
    float* zbuf = hf + 3 * NZ;
    float* f1   = zbuf + 3 * NZ;
    float* fs   = f1 + 3 * NF;
    ushort_t* xf_l = (ushort_t*)(fs + 3 * NF);           // T*N*320
    ushort_t* xf_a = xf_l + (size_t)T_DIM * N_DIM * 320; // T*N*96
    ushort_t* xf_v = xf_a + (size_t)T_DIM * N_DIM * 96;  // T*N*64
    size_t need = (size_t)((char*)(xf_v + (size_t)T_DIM * N_DIM * 64) - wsb);
    if (ws_size < need) return;

    // zero initial h
    hipMemsetAsync(h0, 0, 3 * NZ * sizeof(ushort_t), stream);

    // output slice copies
    split_kernel<<<4096, 256, 0, stream>>>(x, out_l, out_a, out_v);

    // x fragment conversion (all timesteps)
    {
        XConvP p{};
        p.x = x;
        p.xf[0] = xf_l; p.xf[1] = xf_a; p.xf[2] = xf_v;
        xconv_kernel<<<61440, 256, 0, stream>>>(p);
    }

    // persistent LSTM
    {
        PersistP pp{};
        pp.xf[0] = xf_l; pp.xf[1] = xf_a; pp.xf[2] = xf_v;
        for (int m = 0; m < 3; ++m) {
            pp.Wih[m] = W_ih[m]; pp.Whh[m] = W_hh[m];
            pp.bih[m] = b_ih[m]; pp.bhh[m] = b_hh[m];
        }
        pp.h0 = h0; pp.h1 = h1;
        void* args[] = {&pp};
        hipLaunchCooperativeKernel((void*)lstm_persist_kernel,
                                   dim3(256), dim3(512), args, 0, stream);
    }

    // final h (in h0 after 64 steps) -> f32
    h2f_kernel<<<(3 * NZ) / 256, 256, 0, stream>>>(h0, hf);

    // z = h @ Wfc^T + bfc
    {
        GemmP p{};
        for (int m = 0; m < 3; ++m) {
            p.A1[m] = hf + m * NZ; p.W1[m] = Wfc[m]; p.K1[m] = ZD;
            p.b1[m] = bfc[m];      p.C[m] = zbuf + m * NZ;
        }
        p.lda1 = ZD; p.ldc = ZD; p.relu = 0;
        gemm3_kernel<<<dim3(N_DIM / 64, ZD / 64, 3), 256, 0, stream>>>(p);
    }
    // f1 = relu(z @ Wh1^T + bh1)
    {
        GemmP p{};
        for (int m = 0; m < 3; ++m) {
            p.A1[m] = zbuf + m * NZ; p.W1[m] = Wh1[m]; p.K1[m] = ZD;
            p.b1[m] = bh1[m];        p.C[m] = f1 + m * NF;
        }
        p.lda1 = ZD; p.ldc = FD; p.relu = 1;
        gemm3_kernel<<<dim3(N_DIM / 64, FD / 64, 3), 256, 0, stream>>>(p);
    }
    // fs[:, m*128:(m+1)*128] = relu(f1 @ Wh2^T + bh2)
    {
        GemmP p{};
        for (int m = 0; m < 3; ++m) {
            p.A1[m] = f1 + m * NF; p.W1[m] = Wh2[m]; p.K1[m] = FD;
            p.b1[m] = bh2[m];      p.C[m] = fs + m * FD;
        }
        p.lda1 = FD; p.ldc = 3 * FD; p.relu = 1;
        gemm3_kernel<<<dim3(N_DIM / 64, FD / 64, 3), 256, 0, stream>>>(p);
    }
    // y
    y_kernel<<<(N_DIM * 64) / 256, 256, 0, stream>>>(fs, Wy, by, out_y);
}

// Round 5
// 2118.884 us; speedup vs baseline: 2.9802x; 1.8552x over previous
//
#include <hip/hip_runtime.h>

typedef __attribute__((ext_vector_type(8))) short short8;
typedef __attribute__((ext_vector_type(4))) float f32x4;
typedef unsigned short ushort_t;

#define T_DIM 64
#define N_DIM 4096
#define DL 300
#define DA 74
#define DV 35
#define DTOT 409
#define ZD 256
#define FD 128
#define KP1_L 320
#define KP1_A 96
#define KP1_V 64

__device__ __forceinline__ ushort_t f2bf(float v) {
    unsigned u = __float_as_uint(v);
    u += 0x7fffu + ((u >> 16) & 1u);
    return (ushort_t)(u >> 16);
}

// ---------------------------------------------------------------------------
// prep: one pass over x -> (1) the three fp32 output slices, (2) bf16
// A-fragment buffers xf[m] : [t][nb][kc][lane][8].
// Block = (t, nb: 16-row group), 256 threads.
// ---------------------------------------------------------------------------
struct PrepP {
    const float* x;
    float* ol;
    float* oa;
    float* ov;
    ushort_t* xf[3];
};
__global__ __launch_bounds__(256) void prep_kernel(PrepP p) {
    __shared__ float xrow[16][420];   // pitch 420: rows 2-way-bank-spread, 16B-aligned
    const int bid = blockIdx.x;
    const int t = bid >> 8, nb = bid & 255;
    const int tid = threadIdx.x;
    const size_t rowbase = (size_t)t * N_DIM + (size_t)nb * 16;

    const float* __restrict__ src = p.x + rowbase * DTOT;
    for (int e = tid; e < 16 * DTOT; e += 256) {
        int r = e / DTOT, d = e - r * DTOT;
        xrow[r][d] = src[e];
    }
    __syncthreads();

    // output slice copies (writes contiguous per slice)
    {
        float* __restrict__ dl = p.ol + rowbase * DL;
        for (int e = tid; e < 16 * DL; e += 256) { int r = e / DL, d = e - r * DL; dl[e] = xrow[r][d]; }
        float* __restrict__ da = p.oa + rowbase * DA;
        for (int e = tid; e < 16 * DA; e += 256) { int r = e / DA, d = e - r * DA; da[e] = xrow[r][300 + d]; }
        float* __restrict__ dv = p.ov + rowbase * DV;
        for (int e = tid; e < 16 * DV; e += 256) { int r = e / DV, d = e - r * DV; dv[e] = xrow[r][374 + d]; }
    }

    // bf16 A-fragments
    const unsigned tnb = (unsigned)t * 256u + (unsigned)nb;
    for (int q = tid; q < 960; q += 256) {
        int m, kc, l, xkc, col0, dcap;
        if (q < 640)      { m = 0; kc = q >> 6;          l = q & 63; xkc = 10; col0 = 0;   dcap = DL; }
        else if (q < 832) { int qq = q - 640; m = 1; kc = qq >> 6; l = qq & 63; xkc = 3; col0 = 300; dcap = DA; }
        else              { int qq = q - 832; m = 2; kc = qq >> 6; l = qq & 63; xkc = 2; col0 = 374; dcap = DV; }
        int n16 = l & 15;
        int kb = kc * 32 + (l >> 4) * 8;
        ushort_t tmp[8];
#pragma unroll
        for (int j = 0; j < 8; ++j) {
            int k = kb + j;
            tmp[j] = (k < dcap) ? f2bf(xrow[n16][col0 + k]) : (ushort_t)0;
        }
        ushort_t* dst = p.xf[m] + (((size_t)tnb * xkc + kc) * 64 + l) * 8;
        *reinterpret_cast<short8*>(dst) = *reinterpret_cast<short8*>(tmp);
    }
}

// ---------------------------------------------------------------------------
// Persistent LSTM, custom device-scope barrier (NO grid.sync / L2 flush).
// 256 blocks x 512 threads, 1 block/CU. Block = (m, 512-row tile r, slice cb).
// Weights in LDS for all 64 steps; c in registers; h exchanged through L3
// via volatile (sc0 sc1) stores/loads in slice-major layout [slice][n][ZW].
// ---------------------------------------------------------------------------
struct PersistP {
    const ushort_t* xf[3];
    const float* Wih[3];
    const float* Whh[3];
    const float* bih[3];
    const float* bhh[3];
    ushort_t* h0;
    ushort_t* h1;
    unsigned* bar;
};

template <int KP1, int ZW, int D>
__device__ __forceinline__ void persist_body(const PersistP& p, int m, int r, int cb,
                                             ushort_t* wl, ushort_t* hstall) {
    constexpr int KT = KP1 + 256;
    constexpr int KC = KT / 32;
    constexpr int XKC = KP1 / 32;
    constexpr int ZHC = ZW / 16;
    constexpr int NCF = 4 * ZHC;
    constexpr int ZWP = ZW + 8;
    const int tid = threadIdx.x;
    const int w = tid >> 6, lane = tid & 63, ln = lane & 15, lg = lane >> 4;
    const int row0 = r * 512 + w * 64;
    const int z0 = cb * ZW;
    const size_t NZm = (size_t)N_DIM * ZD;

    // ---- stage weights into LDS (B-fragment order), once ----
    {
        const float* __restrict__ Wih = p.Wih[m];
        const float* __restrict__ Whh = p.Whh[m];
        for (int e = tid; e < NCF * KC * 64; e += 512) {
            int l = e & 63;
            int rk = e >> 6;
            int kc = rk % KC, cf = rk / KC;
            int gate = cf / ZHC, zh = cf - gate * ZHC;
            int grow = gate * 256 + z0 + zh * 16 + (l & 15);
            int kb = kc * 32 + (l >> 4) * 8;
            ushort_t tmp[8];
#pragma unroll
            for (int j = 0; j < 8; ++j) {
                int k = kb + j;
                float v = 0.f;
                if (k < D) v = Wih[(size_t)grow * D + k];
                else if (k >= KP1) v = Whh[(size_t)grow * 256 + (k - KP1)];
                tmp[j] = f2bf(v);
            }
            *reinterpret_cast<short8*>(&wl[e * 8]) = *reinterpret_cast<short8*>(tmp);
        }
    }
    __syncthreads();

    float bi[ZHC], bf_[ZHC], bg[ZHC], bo[ZHC];
#pragma unroll
    for (int zh = 0; zh < ZHC; ++zh) {
        int z = z0 + zh * 16 + ln;
        bi[zh]  = p.bih[m][z] + p.bhh[m][z];
        bf_[zh] = p.bih[m][256 + z] + p.bhh[m][256 + z];
        bg[zh]  = p.bih[m][512 + z] + p.bhh[m][512 + z];
        bo[zh]  = p.bih[m][768 + z] + p.bhh[m][768 + z];
    }

    const ushort_t* __restrict__ xf = p.xf[m];
    ushort_t* hb0 = p.h0 + (size_t)m * NZm;
    ushort_t* hb1 = p.h1 + (size_t)m * NZm;
    ushort_t* hst = hstall + w * 64 * ZWP;
    const int nb0 = row0 >> 4;
    float creg[4][ZHC][4] = {};

#pragma unroll 1
    for (int t = 0; t < T_DIM; ++t) {
        const ushort_t* hcm = (t & 1) ? hb1 : hb0;
        ushort_t* hnm = (t & 1) ? hb0 : hb1;
        f32x4 acc[4][NCF] = {};

        // ---- x-part (no h dependency; overlaps barrier wait skew) ----
#pragma unroll 1
        for (int kc = 0; kc < XKC; ++kc) {
            short8 a[4];
#pragma unroll
            for (int rf = 0; rf < 4; ++rf)
                a[rf] = *reinterpret_cast<const short8*>(
                    xf + ((((size_t)t * 256 + nb0 + rf) * XKC + kc) * 64 + lane) * 8);
#pragma unroll
            for (int cf = 0; cf < NCF; ++cf) {
                short8 b = *reinterpret_cast<const short8*>(&wl[((cf * KC + kc) * 64 + lane) * 8]);
#pragma unroll
                for (int rf = 0; rf < 4; ++rf)
                    acc[rf][cf] = __builtin_amdgcn_mfma_f32_16x16x32_bf16(
                        a[rf], b, acc[rf][cf], 0, 0, 0);
            }
        }

        // ---- wait for step t-1 of all 256 blocks ----
        if (t > 0) {
            if (tid == 0) {
                unsigned tgt = 256u * (unsigned)t;
                while (__hip_atomic_load(p.bar, __ATOMIC_RELAXED, __HIP_MEMORY_SCOPE_AGENT) < tgt)
                    __builtin_amdgcn_s_sleep(2);
            }
            __syncthreads();
        }

        // ---- h-part: device-coherent loads (bypass stale L2) ----
#pragma unroll 1
        for (int kc2 = 0; kc2 < 8; ++kc2) {
            short8 a[4];
#pragma unroll
            for (int rf = 0; rf < 4; ++rf) {
                const ushort_t* hp;
                if (ZW == 32)
                    hp = hcm + ((size_t)kc2 * N_DIM + (row0 + rf * 16 + ln)) * 32 + lg * 8;
                else
                    hp = hcm + ((size_t)(kc2 * 2 + (lg >> 1)) * N_DIM + (row0 + rf * 16 + ln)) * 16
                         + (lg & 1) * 8;
                a[rf] = *(const volatile short8*)hp;
            }
#pragma unroll
            for (int cf = 0; cf < NCF; ++cf) {
                short8 b = *reinterpret_cast<const short8*>(&wl[((cf * KC + XKC + kc2) * 64 + lane) * 8]);
#pragma unroll
                for (int rf = 0; rf < 4; ++rf)
                    acc[rf][cf] = __builtin_amdgcn_mfma_f32_16x16x32_bf16(
                        a[rf], b, acc[rf][cf], 0, 0, 0);
            }
        }

        // ---- pointwise epilogue -> per-wave LDS stage ----
#pragma unroll
        for (int rf = 0; rf < 4; ++rf)
#pragma unroll
            for (int zh = 0; zh < ZHC; ++zh)
#pragma unroll
                for (int reg = 0; reg < 4; ++reg) {
                    float gi = acc[rf][0 * ZHC + zh][reg] + bi[zh];
                    float gf = acc[rf][1 * ZHC + zh][reg] + bf_[zh];
                    float gg = acc[rf][2 * ZHC + zh][reg] + bg[zh];
                    float go = acc[rf][3 * ZHC + zh][reg] + bo[zh];
                    float i_ = 1.f / (1.f + __expf(-gi));
                    float f_ = 1.f / (1.f + __expf(-gf));
                    float g_ = 1.f - 2.f / (1.f + __expf(2.f * gg));
                    float o_ = 1.f / (1.f + __expf(-go));
                    float cc = f_ * creg[rf][zh][reg] + i_ * g_;
                    creg[rf][zh][reg] = cc;
                    float hh = o_ * (1.f - 2.f / (1.f + __expf(2.f * cc)));
                    hst[(rf * 16 + lg * 4 + reg) * ZWP + zh * 16 + ln] = f2bf(hh);
                }
        __syncthreads();

        // ---- coalesced device-coherent h store: [slice cb][row][ZW] ----
#pragma unroll
        for (int rd = 0; rd < ZW / 8; ++rd) {
            int el = rd * 512 + lane * 8;
            int rw = el / ZW, zo = el - rw * ZW;
            short8 v = *reinterpret_cast<const short8*>(&hst[rw * ZWP + zo]);
            ushort_t* dst = hnm + ((size_t)cb * N_DIM + row0 + rw) * ZW + zo;
            *(volatile short8*)dst = v;
        }
        asm volatile("s_waitcnt vmcnt(0)" ::: "memory");
        __syncthreads();
        if (tid == 0)
            __hip_atomic_fetch_add(p.bar, 1u, __ATOMIC_RELAXED, __HIP_MEMORY_SCOPE_AGENT);
    }
}

__global__ __launch_bounds__(512, 2) void lstm_persist_kernel(PersistP p) {
    __shared__ ushort_t sh[65536];   // 90112B weights + 40960B h-stage
    ushort_t* wl = sh;
    ushort_t* hstall = sh + 45056;
    const int bid = blockIdx.x;
    const int r = bid & 7;
    const int idx = bid >> 3;
    if (idx < 16)      persist_body<KP1_L, 16, DL>(p, 0, r, idx, wl, hstall);
    else if (idx < 24) persist_body<KP1_A, 32, DA>(p, 1, r, idx - 16, wl, hstall);
    else               persist_body<KP1_V, 32, DV>(p, 2, r, idx - 24, wl, hstall);
}

// ---------------------------------------------------------------------------
// h (slice-major bf16) -> hf fp32 [m][n][z]
// ---------------------------------------------------------------------------
__global__ __launch_bounds__(256) void h2f_kernel(const ushort_t* __restrict__ h,
                                                  float* __restrict__ hf) {
    unsigned i = blockIdx.x * 256u + threadIdx.x;
    const unsigned NZu = (unsigned)N_DIM * ZD;
    unsigned m = i / NZu, rzn = i - m * NZu;
    unsigned n = rzn >> 8, z = rzn & 255u;
    unsigned zw = (m == 0) ? 16u : 32u;
    unsigned slice = z / zw, zo = z - slice * zw;
    ushort_t v = h[(size_t)m * NZu + ((size_t)slice * N_DIM + n) * zw + zo];
    hf[i] = __uint_as_float(((unsigned)v) << 16);
}

// ---------------------------------------------------------------------------
// fp32 tiled GEMM for the head layers
// ---------------------------------------------------------------------------
struct GemmP {
    const float* A1[3];
    const float* W1[3];
    const float* b1[3];
    float* C[3];
    int K1[3];
    int lda1;
    int ldc;
    int relu;
};

__device__ __forceinline__ void mac16(const float (&As)[16][64], const float (&Ws)[16][64],
                                      int tx, int ty, float (&acc)[4][4]) {
#pragma unroll
    for (int k = 0; k < 16; ++k) {
        float4 av = *reinterpret_cast<const float4*>(&As[k][ty * 4]);
        float4 bv = *reinterpret_cast<const float4*>(&Ws[k][tx * 4]);
        float a[4] = {av.x, av.y, av.z, av.w};
        float b[4] = {bv.x, bv.y, bv.z, bv.w};
#pragma unroll
        for (int i = 0; i < 4; ++i)
#pragma unroll
            for (int j = 0; j < 4; ++j)
                acc[i][j] = fmaf(a[i], b[j], acc[i][j]);
    }
}

__global__ __launch_bounds__(256) void gemm3_kernel(GemmP p) {
    const int m = blockIdx.z;
    const float* __restrict__ A1 = p.A1[m];
    const float* __restrict__ W1 = p.W1[m];
    const int K1 = p.K1[m];
    float* __restrict__ C = p.C[m];
    const int row0 = blockIdx.x * 64;
    const int col0 = blockIdx.y * 64;

    __shared__ __align__(16) float As[16][64];
    __shared__ __align__(16) float Ws[16][64];

    const int tid = threadIdx.x;
    const int tx = tid & 15, ty = tid >> 4;
    float acc[4][4] = {};

    for (int k0 = 0; k0 < K1; k0 += 16) {
#pragma unroll
        for (int i = 0; i < 4; ++i) {
            int e = tid * 4 + i;
            int rr = e >> 4, k = e & 15;
            int kk = k0 + k;
            As[k][rr] = (kk < K1) ? A1[(size_t)(row0 + rr) * p.lda1 + kk] : 0.f;
            Ws[k][rr] = (kk < K1) ? W1[(size_t)(col0 + rr) * K1 + kk] : 0.f;
        }
        __syncthreads();
        mac16(As, Ws, tx, ty, acc);
        __syncthreads();
    }

    const float* __restrict__ b1 = p.b1[m];
#pragma unroll
    for (int i = 0; i < 4; ++i) {
        int rr = row0 + ty * 4 + i;
        float v[4];
#pragma unroll
        for (int j = 0; j < 4; ++j) {
            int cc = col0 + tx * 4 + j;
            float tvl = acc[i][j] + b1[cc];
            if (p.relu) tvl = fmaxf(tvl, 0.f);
            v[j] = tvl;
        }
        float4 o = make_float4(v[0], v[1], v[2], v[3]);
        *reinterpret_cast<float4*>(&C[(size_t)rr * p.ldc + col0 + tx * 4]) = o;
    }
}

// ---------------------------------------------------------------------------
// y[n] = dot(fs[n,:384], Wy) + by
// ---------------------------------------------------------------------------
__global__ __launch_bounds__(256) void y_kernel(const float* __restrict__ fs,
                                                const float* __restrict__ Wy,
                                                const float* __restrict__ by,
                                                float* __restrict__ y) {
    unsigned wave = (blockIdx.x * 256u + threadIdx.x) >> 6;
    unsigned lane = threadIdx.x & 63u;
    if (wave >= N_DIM) return;
    const float* row = fs + (size_t)wave * 3 * FD;
    float s = 0.f;
    for (unsigned j = lane; j < 3 * FD; j += 64) s += row[j] * Wy[j];
#pragma unroll
    for (int off = 32; off; off >>= 1) s += __shfl_down(s, off);
    if (lane == 0) y[wave] = s + by[0];
}

extern "C" void kernel_launch(void* const* d_in, const int* in_sizes, int n_in,
                              void* d_out, int out_size, void* d_ws, size_t ws_size,
                              hipStream_t stream) {
    const float* x = (const float*)d_in[0];
    const float *W_ih[3], *W_hh[3], *b_ih[3], *b_hh[3], *Wfc[3], *bfc[3],
                *Wh1[3], *bh1[3], *Wh2[3], *bh2[3];
    for (int m = 0; m < 3; ++m) {
        const int b = 1 + m * 10;
        W_ih[m] = (const float*)d_in[b + 0];
        W_hh[m] = (const float*)d_in[b + 1];
        b_ih[m] = (const float*)d_in[b + 2];
        b_hh[m] = (const float*)d_in[b + 3];
        Wfc[m]  = (const float*)d_in[b + 4];
        bfc[m]  = (const float*)d_in[b + 5];
        Wh1[m]  = (const float*)d_in[b + 6];
        bh1[m]  = (const float*)d_in[b + 7];
        Wh2[m]  = (const float*)d_in[b + 8];
        bh2[m]  = (const float*)d_in[b + 9];
    }
    const float* Wy = (const float*)d_in[31];
    const float* by = (const float*)d_in[32];

    float* out   = (float*)d_out;
    float* out_l = out;
    float* out_a = out_l + (size_t)T_DIM * N_DIM * DL;
    float* out_v = out_a + (size_t)T_DIM * N_DIM * DA;
    float* out_y = out_v + (size_t)T_DIM * N_DIM * DV;

    const size_t NZ = (size_t)N_DIM * ZD;
    const size_t NF = (size_t)N_DIM * FD;

    // workspace layout
    char* wsb = (char*)d_ws;
    unsigned* bar = (unsigned*)wsb;                         // 256 B
    ushort_t* h0 = (ushort_t*)(wsb + 256);                  // 3NZ bf16
    ushort_t* h1 = h0 + 3 * NZ;                             // 3NZ bf16
    float* hf   = (float*)(h1 + 3 * NZ);                    // 3NZ f32
    float* zbuf = hf + 3 * NZ;
    float* f1   = zbuf + 3 * NZ;
    float* fs   = f1 + 3 * NF;
    ushort_t* xf_l = (ushort_t*)(fs + 3 * NF);              // T*N*320
    ushort_t* xf_a = xf_l + (size_t)T_DIM * N_DIM * KP1_L;  // T*N*96
    ushort_t* xf_v = xf_a + (size_t)T_DIM * N_DIM * KP1_A;  // T*N*64
    size_t need = (size_t)((char*)(xf_v + (size_t)T_DIM * N_DIM * KP1_V) - wsb);
    if (ws_size < need) return;

    // zero barrier counter + initial h0
    hipMemsetAsync(wsb, 0, 256 + 3 * NZ * sizeof(ushort_t), stream);

    // fused split + fragment conversion
    {
        PrepP p{};
        p.x = x;
        p.ol = out_l; p.oa = out_a; p.ov = out_v;
        p.xf[0] = xf_l; p.xf[1] = xf_a; p.xf[2] = xf_v;
        prep_kernel<<<T_DIM * 256, 256, 0, stream>>>(p);
    }

    // persistent LSTM (cooperative launch for co-residency guarantee)
    {
        PersistP pp{};
        pp.xf[0] = xf_l; pp.xf[1] = xf_a; pp.xf[2] = xf_v;
        for (int m = 0; m < 3; ++m) {
            pp.Wih[m] = W_ih[m]; pp.Whh[m] = W_hh[m];
            pp.bih[m] = b_ih[m]; pp.bhh[m] = b_hh[m];
        }
        pp.h0 = h0; pp.h1 = h1; pp.bar = bar;
        void* args[] = {&pp};
        hipLaunchCooperativeKernel((void*)lstm_persist_kernel,
                                   dim3(256), dim3(512), args, 0, stream);
    }

    // final h (in h0 after 64 steps) -> f32 [m][n][z]
    h2f_kernel<<<(3 * NZ) / 256, 256, 0, stream>>>(h0, hf);

    // z = h @ Wfc^T + bfc
    {
        GemmP p{};
        for (int m = 0; m < 3; ++m) {
            p.A1[m] = hf + m * NZ; p.W1[m] = Wfc[m]; p.K1[m] = ZD;
            p.b1[m] = bfc[m];      p.C[m] = zbuf + m * NZ;
        }
        p.lda1 = ZD; p.ldc = ZD; p.relu = 0;
        gemm3_kernel<<<dim3(N_DIM / 64, ZD / 64, 3), 256, 0, stream>>>(p);
    }
    // f1 = relu(z @ Wh1^T + bh1)
    {
        GemmP p{};
        for (int m = 0; m < 3; ++m) {
            p.A1[m] = zbuf + m * NZ; p.W1[m] = Wh1[m]; p.K1[m] = ZD;
            p.b1[m] = bh1[m];        p.C[m] = f1 + m * NF;
        }
        p.lda1 = ZD; p.ldc = FD; p.relu = 1;
        gemm3_kernel<<<dim3(N_DIM / 64, FD / 64, 3), 256, 0, stream>>>(p);
    }
    // fs[:, m*128:(m+1)*128] = relu(f1 @ Wh2^T + bh2)
    {
        GemmP p{};
        for (int m = 0; m < 3; ++m) {
            p.A1[m] = f1 + m * NF; p.W1[m] = Wh2[m]; p.K1[m] = FD;
            p.b1[m] = bh2[m];      p.C[m] = fs + m * FD;
        }
        p.lda1 = FD; p.ldc = 3 * FD; p.relu = 1;
        gemm3_kernel<<<dim3(N_DIM / 64, FD / 64, 3), 256, 0, stream>>>(p);
    }
    // y
    y_kernel<<<(N_DIM * 64) / 256, 256, 0, stream>>>(fs, Wy, by, out_y);
}

// Round 6
// 2107.171 us; speedup vs baseline: 2.9967x; 1.0056x over previous
//
#include <hip/hip_runtime.h>

typedef __attribute__((ext_vector_type(8))) short short8;
typedef __attribute__((ext_vector_type(4))) float f32x4;
typedef unsigned short ushort_t;

#define T_DIM 64
#define N_DIM 4096
#define DL 300
#define DA 74
#define DV 35
#define DTOT 409
#define ZD 256
#define FD 128
#define KP1_L 320
#define KP1_A 96
#define KP1_V 64

__device__ __forceinline__ ushort_t f2bf(float v) {
    unsigned u = __float_as_uint(v);
    u += 0x7fffu + ((u >> 16) & 1u);
    return (ushort_t)(u >> 16);
}

// ---------------------------------------------------------------------------
// prep: one pass over x -> (1) the three fp32 output slices, (2) bf16
// A-fragment buffers xf[m] : [t][nb][kc][lane][8].
// ---------------------------------------------------------------------------
struct PrepP {
    const float* x;
    float* ol;
    float* oa;
    float* ov;
    ushort_t* xf[3];
};
__global__ __launch_bounds__(256) void prep_kernel(PrepP p) {
    __shared__ float xrow[16][420];
    const int bid = blockIdx.x;
    const int t = bid >> 8, nb = bid & 255;
    const int tid = threadIdx.x;
    const size_t rowbase = (size_t)t * N_DIM + (size_t)nb * 16;

    const float* __restrict__ src = p.x + rowbase * DTOT;
    for (int e = tid; e < 16 * DTOT; e += 256) {
        int r = e / DTOT, d = e - r * DTOT;
        xrow[r][d] = src[e];
    }
    __syncthreads();

    {
        float* __restrict__ dl = p.ol + rowbase * DL;
        for (int e = tid; e < 16 * DL; e += 256) { int r = e / DL, d = e - r * DL; dl[e] = xrow[r][d]; }
        float* __restrict__ da = p.oa + rowbase * DA;
        for (int e = tid; e < 16 * DA; e += 256) { int r = e / DA, d = e - r * DA; da[e] = xrow[r][300 + d]; }
        float* __restrict__ dv = p.ov + rowbase * DV;
        for (int e = tid; e < 16 * DV; e += 256) { int r = e / DV, d = e - r * DV; dv[e] = xrow[r][374 + d]; }
    }

    const unsigned tnb = (unsigned)t * 256u + (unsigned)nb;
    for (int q = tid; q < 960; q += 256) {
        int m, kc, l, xkc, col0, dcap;
        if (q < 640)      { m = 0; kc = q >> 6;          l = q & 63; xkc = 10; col0 = 0;   dcap = DL; }
        else if (q < 832) { int qq = q - 640; m = 1; kc = qq >> 6; l = qq & 63; xkc = 3; col0 = 300; dcap = DA; }
        else              { int qq = q - 832; m = 2; kc = qq >> 6; l = qq & 63; xkc = 2; col0 = 374; dcap = DV; }
        int n16 = l & 15;
        int kb = kc * 32 + (l >> 4) * 8;
        ushort_t tmp[8];
#pragma unroll
        for (int j = 0; j < 8; ++j) {
            int k = kb + j;
            tmp[j] = (k < dcap) ? f2bf(xrow[n16][col0 + k]) : (ushort_t)0;
        }
        ushort_t* dst = p.xf[m] + (((size_t)tnb * xkc + kc) * 64 + l) * 8;
        *reinterpret_cast<short8*>(dst) = *reinterpret_cast<short8*>(tmp);
    }
}

// ---------------------------------------------------------------------------
// Persistent LSTM with GROUP-LOCAL flag barriers (no global atomic counter).
// 256 blocks x 512 threads. Block = (m, 512-row tile r, slice cb).
// Sync group = blocks sharing (m, r): 16 for L, 8 for A/V; members are bids
// stride-8 apart (co-XCD under %8 round-robin). Each block posts its own
// flag word (64B apart) after its h-store drains; consumers poll their
// group's flags only. h exchanged device-coherent (volatile -> L3).
// ---------------------------------------------------------------------------
struct PersistP {
    const ushort_t* xf[3];
    const float* Wih[3];
    const float* Whh[3];
    const float* bih[3];
    const float* bhh[3];
    ushort_t* h0;
    ushort_t* h1;
    unsigned* flags;   // [256] block flags at stride 16 u32 (64B)
};

template <int KP1, int ZW, int D>
__device__ __forceinline__ void persist_body(const PersistP& p, int m, int r, int cb,
                                             int bid, int idxbase, int gsz,
                                             ushort_t* wl, ushort_t* hstall) {
    constexpr int KT = KP1 + 256;
    constexpr int KC = KT / 32;
    constexpr int XKC = KP1 / 32;
    constexpr int ZHC = ZW / 16;
    constexpr int NCF = 4 * ZHC;
    constexpr int ZWP = ZW + 8;
    const int tid = threadIdx.x;
    const int w = tid >> 6, lane = tid & 63, ln = lane & 15, lg = lane >> 4;
    const int row0 = r * 512 + w * 64;
    const int z0 = cb * ZW;
    const size_t NZm = (size_t)N_DIM * ZD;

    // ---- stage weights into LDS (B-fragment order), once ----
    {
        const float* __restrict__ Wih = p.Wih[m];
        const float* __restrict__ Whh = p.Whh[m];
        for (int e = tid; e < NCF * KC * 64; e += 512) {
            int l = e & 63;
            int rk = e >> 6;
            int kc = rk % KC, cf = rk / KC;
            int gate = cf / ZHC, zh = cf - gate * ZHC;
            int grow = gate * 256 + z0 + zh * 16 + (l & 15);
            int kb = kc * 32 + (l >> 4) * 8;
            ushort_t tmp[8];
#pragma unroll
            for (int j = 0; j < 8; ++j) {
                int k = kb + j;
                float v = 0.f;
                if (k < D) v = Wih[(size_t)grow * D + k];
                else if (k >= KP1) v = Whh[(size_t)grow * 256 + (k - KP1)];
                tmp[j] = f2bf(v);
            }
            *reinterpret_cast<short8*>(&wl[e * 8]) = *reinterpret_cast<short8*>(tmp);
        }
    }
    __syncthreads();

    float bi[ZHC], bf_[ZHC], bg[ZHC], bo[ZHC];
#pragma unroll
    for (int zh = 0; zh < ZHC; ++zh) {
        int z = z0 + zh * 16 + ln;
        bi[zh]  = p.bih[m][z] + p.bhh[m][z];
        bf_[zh] = p.bih[m][256 + z] + p.bhh[m][256 + z];
        bg[zh]  = p.bih[m][512 + z] + p.bhh[m][512 + z];
        bo[zh]  = p.bih[m][768 + z] + p.bhh[m][768 + z];
    }

    const ushort_t* __restrict__ xf = p.xf[m];
    ushort_t* hb0 = p.h0 + (size_t)m * NZm;
    ushort_t* hb1 = p.h1 + (size_t)m * NZm;
    ushort_t* hst = hstall + w * 64 * ZWP;
    const int nb0 = row0 >> 4;
    float creg[4][ZHC][4] = {};

#pragma unroll 1
    for (int t = 0; t < T_DIM; ++t) {
        const ushort_t* hcm = (t & 1) ? hb1 : hb0;
        ushort_t* hnm = (t & 1) ? hb0 : hb1;
        f32x4 acc[4][NCF] = {};

        // ---- x-part (no h dependency; overlaps barrier wait skew) ----
#pragma unroll 1
        for (int kc = 0; kc < XKC; ++kc) {
            short8 a[4];
#pragma unroll
            for (int rf = 0; rf < 4; ++rf)
                a[rf] = *reinterpret_cast<const short8*>(
                    xf + ((((size_t)t * 256 + nb0 + rf) * XKC + kc) * 64 + lane) * 8);
#pragma unroll
            for (int cf = 0; cf < NCF; ++cf) {
                short8 b = *reinterpret_cast<const short8*>(&wl[((cf * KC + kc) * 64 + lane) * 8]);
#pragma unroll
                for (int rf = 0; rf < 4; ++rf)
                    acc[rf][cf] = __builtin_amdgcn_mfma_f32_16x16x32_bf16(
                        a[rf], b, acc[rf][cf], 0, 0, 0);
            }
        }

        // ---- group-local wait: all members finished step t-1 ----
        if (t > 0) {
            if (w == 0 && lane < gsz) {
                const unsigned* fp = p.flags + (size_t)((idxbase + lane) * 8 + r) * 16;
                while (__hip_atomic_load(fp, __ATOMIC_RELAXED, __HIP_MEMORY_SCOPE_AGENT)
                       < (unsigned)t)
                    __builtin_amdgcn_s_sleep(1);
            }
            __syncthreads();
        }

        // ---- h-part: device-coherent loads ----
#pragma unroll 1
        for (int kc2 = 0; kc2 < 8; ++kc2) {
            short8 a[4];
#pragma unroll
            for (int rf = 0; rf < 4; ++rf) {
                const ushort_t* hp;
                if (ZW == 32)
                    hp = hcm + ((size_t)kc2 * N_DIM + (row0 + rf * 16 + ln)) * 32 + lg * 8;
                else
                    hp = hcm + ((size_t)(kc2 * 2 + (lg >> 1)) * N_DIM + (row0 + rf * 16 + ln)) * 16
                         + (lg & 1) * 8;
                a[rf] = *(const volatile short8*)hp;
            }
#pragma unroll
            for (int cf = 0; cf < NCF; ++cf) {
                short8 b = *reinterpret_cast<const short8*>(&wl[((cf * KC + XKC + kc2) * 64 + lane) * 8]);
#pragma unroll
                for (int rf = 0; rf < 4; ++rf)
                    acc[rf][cf] = __builtin_amdgcn_mfma_f32_16x16x32_bf16(
                        a[rf], b, acc[rf][cf], 0, 0, 0);
            }
        }

        // ---- pointwise epilogue -> per-wave LDS stage ----
#pragma unroll
        for (int rf = 0; rf < 4; ++rf)
#pragma unroll
            for (int zh = 0; zh < ZHC; ++zh)
#pragma unroll
                for (int reg = 0; reg < 4; ++reg) {
                    float gi = acc[rf][0 * ZHC + zh][reg] + bi[zh];
                    float gf = acc[rf][1 * ZHC + zh][reg] + bf_[zh];
                    float gg = acc[rf][2 * ZHC + zh][reg] + bg[zh];
                    float go = acc[rf][3 * ZHC + zh][reg] + bo[zh];
                    float i_ = 1.f / (1.f + __expf(-gi));
                    float f_ = 1.f / (1.f + __expf(-gf));
                    float g_ = 1.f - 2.f / (1.f + __expf(2.f * gg));
                    float o_ = 1.f / (1.f + __expf(-go));
                    float cc = f_ * creg[rf][zh][reg] + i_ * g_;
                    creg[rf][zh][reg] = cc;
                    float hh = o_ * (1.f - 2.f / (1.f + __expf(2.f * cc)));
                    hst[(rf * 16 + lg * 4 + reg) * ZWP + zh * 16 + ln] = f2bf(hh);
                }
        __syncthreads();

        // ---- coalesced device-coherent h store: [slice cb][row][ZW] ----
#pragma unroll
        for (int rd = 0; rd < ZW / 8; ++rd) {
            int el = rd * 512 + lane * 8;
            int rw = el / ZW, zo = el - rw * ZW;
            short8 v = *reinterpret_cast<const short8*>(&hst[rw * ZWP + zo]);
            ushort_t* dst = hnm + ((size_t)cb * N_DIM + row0 + rw) * ZW + zo;
            *(volatile short8*)dst = v;
        }
        asm volatile("s_waitcnt vmcnt(0)" ::: "memory");
        __syncthreads();
        if (tid == 0)
            __hip_atomic_store(p.flags + (size_t)bid * 16, (unsigned)(t + 1),
                               __ATOMIC_RELAXED, __HIP_MEMORY_SCOPE_AGENT);
    }
}

__global__ __launch_bounds__(512, 2) void lstm_persist_kernel(PersistP p) {
    __shared__ ushort_t sh[65536];   // 90112B weights + 40960B h-stage
    ushort_t* wl = sh;
    ushort_t* hstall = sh + 45056;
    const int bid = blockIdx.x;
    const int r = bid & 7;
    const int idx = bid >> 3;
    if (idx < 16)      persist_body<KP1_L, 16, DL>(p, 0, r, idx, bid, 0, 16, wl, hstall);
    else if (idx < 24) persist_body<KP1_A, 32, DA>(p, 1, r, idx - 16, bid, 16, 8, wl, hstall);
    else               persist_body<KP1_V, 32, DV>(p, 2, r, idx - 24, bid, 24, 8, wl, hstall);
}

// ---------------------------------------------------------------------------
// h (slice-major bf16) -> hf fp32 [m][n][z]
// ---------------------------------------------------------------------------
__global__ __launch_bounds__(256) void h2f_kernel(const ushort_t* __restrict__ h,
                                                  float* __restrict__ hf) {
    unsigned i = blockIdx.x * 256u + threadIdx.x;
    const unsigned NZu = (unsigned)N_DIM * ZD;
    unsigned m = i / NZu, rzn = i - m * NZu;
    unsigned n = rzn >> 8, z = rzn & 255u;
    unsigned zw = (m == 0) ? 16u : 32u;
    unsigned slice = z / zw, zo = z - slice * zw;
    ushort_t v = h[(size_t)m * NZu + ((size_t)slice * N_DIM + n) * zw + zo];
    hf[i] = __uint_as_float(((unsigned)v) << 16);
}

// ---------------------------------------------------------------------------
// fp32 tiled GEMM for the head layers
// ---------------------------------------------------------------------------
struct GemmP {
    const float* A1[3];
    const float* W1[3];
    const float* b1[3];
    float* C[3];
    int K1[3];
    int lda1;
    int ldc;
    int relu;
};

__device__ __forceinline__ void mac16(const float (&As)[16][64], const float (&Ws)[16][64],
                                      int tx, int ty, float (&acc)[4][4]) {
#pragma unroll
    for (int k = 0; k < 16; ++k) {
        float4 av = *reinterpret_cast<const float4*>(&As[k][ty * 4]);
        float4 bv = *reinterpret_cast<const float4*>(&Ws[k][tx * 4]);
        float a[4] = {av.x, av.y, av.z, av.w};
        float b[4] = {bv.x, bv.y, bv.z, bv.w};
#pragma unroll
        for (int i = 0; i < 4; ++i)
#pragma unroll
            for (int j = 0; j < 4; ++j)
                acc[i][j] = fmaf(a[i], b[j], acc[i][j]);
    }
}

__global__ __launch_bounds__(256) void gemm3_kernel(GemmP p) {
    const int m = blockIdx.z;
    const float* __restrict__ A1 = p.A1[m];
    const float* __restrict__ W1 = p.W1[m];
    const int K1 = p.K1[m];
    float* __restrict__ C = p.C[m];
    const int row0 = blockIdx.x * 64;
    const int col0 = blockIdx.y * 64;

    __shared__ __align__(16) float As[16][64];
    __shared__ __align__(16) float Ws[16][64];

    const int tid = threadIdx.x;
    const int tx = tid & 15, ty = tid >> 4;
    float acc[4][4] = {};

    for (int k0 = 0; k0 < K1; k0 += 16) {
#pragma unroll
        for (int i = 0; i < 4; ++i) {
            int e = tid * 4 + i;
            int rr = e >> 4, k = e & 15;
            int kk = k0 + k;
            As[k][rr] = (kk < K1) ? A1[(size_t)(row0 + rr) * p.lda1 + kk] : 0.f;
            Ws[k][rr] = (kk < K1) ? W1[(size_t)(col0 + rr) * K1 + kk] : 0.f;
        }
        __syncthreads();
        mac16(As, Ws, tx, ty, acc);
        __syncthreads();
    }

    const float* __restrict__ b1 = p.b1[m];
#pragma unroll
    for (int i = 0; i < 4; ++i) {
        int rr = row0 + ty * 4 + i;
        float v[4];
#pragma unroll
        for (int j = 0; j < 4; ++j) {
            int cc = col0 + tx * 4 + j;
            float tvl = acc[i][j] + b1[cc];
            if (p.relu) tvl = fmaxf(tvl, 0.f);
            v[j] = tvl;
        }
        float4 o = make_float4(v[0], v[1], v[2], v[3]);
        *reinterpret_cast<float4*>(&C[(size_t)rr * p.ldc + col0 + tx * 4]) = o;
    }
}

// ---------------------------------------------------------------------------
// y[n] = dot(fs[n,:384], Wy) + by
// ---------------------------------------------------------------------------
__global__ __launch_bounds__(256) void y_kernel(const float* __restrict__ fs,
                                                const float* __restrict__ Wy,
                                                const float* __restrict__ by,
                                                float* __restrict__ y) {
    unsigned wave = (blockIdx.x * 256u + threadIdx.x) >> 6;
    unsigned lane = threadIdx.x & 63u;
    if (wave >= N_DIM) return;
    const float* row = fs + (size_t)wave * 3 * FD;
    float s = 0.f;
    for (unsigned j = lane; j < 3 * FD; j += 64) s += row[j] * Wy[j];
#pragma unroll
    for (int off = 32; off; off >>= 1) s += __shfl_down(s, off);
    if (lane == 0) y[wave] = s + by[0];
}

extern "C" void kernel_launch(void* const* d_in, const int* in_sizes, int n_in,
                              void* d_out, int out_size, void* d_ws, size_t ws_size,
                              hipStream_t stream) {
    const float* x = (const float*)d_in[0];
    const float *W_ih[3], *W_hh[3], *b_ih[3], *b_hh[3], *Wfc[3], *bfc[3],
                *Wh1[3], *bh1[3], *Wh2[3], *bh2[3];
    for (int m = 0; m < 3; ++m) {
        const int b = 1 + m * 10;
        W_ih[m] = (const float*)d_in[b + 0];
        W_hh[m] = (const float*)d_in[b + 1];
        b_ih[m] = (const float*)d_in[b + 2];
        b_hh[m] = (const float*)d_in[b + 3];
        Wfc[m]  = (const float*)d_in[b + 4];
        bfc[m]  = (const float*)d_in[b + 5];
        Wh1[m]  = (const float*)d_in[b + 6];
        bh1[m]  = (const float*)d_in[b + 7];
        Wh2[m]  = (const float*)d_in[b + 8];
        bh2[m]  = (const float*)d_in[b + 9];
    }
    const float* Wy = (const float*)d_in[31];
    const float* by = (const float*)d_in[32];

    float* out   = (float*)d_out;
    float* out_l = out;
    float* out_a = out_l + (size_t)T_DIM * N_DIM * DL;
    float* out_v = out_a + (size_t)T_DIM * N_DIM * DA;
    float* out_y = out_v + (size_t)T_DIM * N_DIM * DV;

    const size_t NZ = (size_t)N_DIM * ZD;
    const size_t NF = (size_t)N_DIM * FD;

    // workspace layout
    char* wsb = (char*)d_ws;
    unsigned* flags = (unsigned*)wsb;                       // 256 x 64B = 16384 B
    ushort_t* h0 = (ushort_t*)(wsb + 16384);                // 3NZ bf16
    ushort_t* h1 = h0 + 3 * NZ;                             // 3NZ bf16
    float* hf   = (float*)(h1 + 3 * NZ);                    // 3NZ f32
    float* zbuf = hf + 3 * NZ;
    float* f1   = zbuf + 3 * NZ;
    float* fs   = f1 + 3 * NF;
    ushort_t* xf_l = (ushort_t*)(fs + 3 * NF);              // T*N*320
    ushort_t* xf_a = xf_l + (size_t)T_DIM * N_DIM * KP1_L;  // T*N*96
    ushort_t* xf_v = xf_a + (size_t)T_DIM * N_DIM * KP1_A;  // T*N*64
    size_t need = (size_t)((char*)(xf_v + (size_t)T_DIM * N_DIM * KP1_V) - wsb);
    if (ws_size < need) return;

    // zero flags + initial h0
    hipMemsetAsync(wsb, 0, 16384 + 3 * NZ * sizeof(ushort_t), stream);

    // fused split + fragment conversion
    {
        PrepP p{};
        p.x = x;
        p.ol = out_l; p.oa = out_a; p.ov = out_v;
        p.xf[0] = xf_l; p.xf[1] = xf_a; p.xf[2] = xf_v;
        prep_kernel<<<T_DIM * 256, 256, 0, stream>>>(p);
    }

    // persistent LSTM (cooperative launch for co-residency guarantee)
    {
        PersistP pp{};
        pp.xf[0] = xf_l; pp.xf[1] = xf_a; pp.xf[2] = xf_v;
        for (int m = 0; m < 3; ++m) {
            pp.Wih[m] = W_ih[m]; pp.Whh[m] = W_hh[m];
            pp.bih[m] = b_ih[m]; pp.bhh[m] = b_hh[m];
        }
        pp.h0 = h0; pp.h1 = h1; pp.flags = flags;
        void* args[] = {&pp};
        hipLaunchCooperativeKernel((void*)lstm_persist_kernel,
                                   dim3(256), dim3(512), args, 0, stream);
    }

    // final h (in h0 after 64 steps) -> f32 [m][n][z]
    h2f_kernel<<<(3 * NZ) / 256, 256, 0, stream>>>(h0, hf);

    // z = h @ Wfc^T + bfc
    {
        GemmP p{};
        for (int m = 0; m < 3; ++m) {
            p.A1[m] = hf + m * NZ; p.W1[m] = Wfc[m]; p.K1[m] = ZD;
            p.b1[m] = bfc[m];      p.C[m] = zbuf + m * NZ;
        }
        p.lda1 = ZD; p.ldc = ZD; p.relu = 0;
        gemm3_kernel<<<dim3(N_DIM / 64, ZD / 64, 3), 256, 0, stream>>>(p);
    }
    // f1 = relu(z @ Wh1^T + bh1)
    {
        GemmP p{};
        for (int m = 0; m < 3; ++m) {
            p.A1[m] = zbuf + m * NZ; p.W1[m] = Wh1[m]; p.K1[m] = ZD;
            p.b1[m] = bh1[m];        p.C[m] = f1 + m * NF;
        }
        p.lda1 = ZD; p.ldc = FD; p.relu = 1;
        gemm3_kernel<<<dim3(N_DIM / 64, FD / 64, 3), 256, 0, stream>>>(p);
    }
    // fs[:, m*128:(m+1)*128] = relu(f1 @ Wh2^T + bh2)
    {
        GemmP p{};
        for (int m = 0; m < 3; ++m) {
            p.A1[m] = f1 + m * NF; p.W1[m] = Wh2[m]; p.K1[m] = FD;
            p.b1[m] = bh2[m];      p.C[m] = fs + m * FD;
        }
        p.lda1 = FD; p.ldc = 3 * FD; p.relu = 1;
        gemm3_kernel<<<dim3(N_DIM / 64, FD / 64, 3), 256, 0, stream>>>(p);
    }
    // y
    y_kernel<<<(N_DIM * 64) / 256, 256, 0, stream>>>(fs, Wy, by, out_y);
}

// Round 7
// 2000.798 us; speedup vs baseline: 3.1561x; 1.0532x over previous
//
#include <hip/hip_runtime.h>

typedef __attribute__((ext_vector_type(8))) short short8;
typedef __attribute__((ext_vector_type(4))) float f32x4;
typedef unsigned short ushort_t;

#define T_DIM 64
#define N_DIM 4096
#define DL 300
#define DA 74
#define DV 35
#define DTOT 409
#define ZD 256
#define FD 128
#define KP1_L 320
#define KP1_A 96
#define KP1_V 64
#define KC_L ((KP1_L + 256) / 32)   // 18
#define KC_A ((KP1_A + 256) / 32)   // 11
#define KC_V ((KP1_V + 256) / 32)   // 10

__device__ __forceinline__ ushort_t f2bf(float v) {
    unsigned u = __float_as_uint(v);
    u += 0x7fffu + ((u >> 16) & 1u);
    return (ushort_t)(u >> 16);
}

// ---------------------------------------------------------------------------
// prep: one pass over x -> (1) the three fp32 output slices, (2) bf16
// A-fragment buffers xf[m] : [t][nb][kc][lane][8].
// ---------------------------------------------------------------------------
struct PrepP {
    const float* x;
    float* ol;
    float* oa;
    float* ov;
    ushort_t* xf[3];
};
__global__ __launch_bounds__(256) void prep_kernel(PrepP p) {
    __shared__ float xrow[16][420];
    const int bid = blockIdx.x;
    const int t = bid >> 8, nb = bid & 255;
    const int tid = threadIdx.x;
    const size_t rowbase = (size_t)t * N_DIM + (size_t)nb * 16;

    const float* __restrict__ src = p.x + rowbase * DTOT;
    for (int e = tid; e < 16 * DTOT; e += 256) {
        int r = e / DTOT, d = e - r * DTOT;
        xrow[r][d] = src[e];
    }
    __syncthreads();

    {
        float* __restrict__ dl = p.ol + rowbase * DL;
        for (int e = tid; e < 16 * DL; e += 256) { int r = e / DL, d = e - r * DL; dl[e] = xrow[r][d]; }
        float* __restrict__ da = p.oa + rowbase * DA;
        for (int e = tid; e < 16 * DA; e += 256) { int r = e / DA, d = e - r * DA; da[e] = xrow[r][300 + d]; }
        float* __restrict__ dv = p.ov + rowbase * DV;
        for (int e = tid; e < 16 * DV; e += 256) { int r = e / DV, d = e - r * DV; dv[e] = xrow[r][374 + d]; }
    }

    const unsigned tnb = (unsigned)t * 256u + (unsigned)nb;
    for (int q = tid; q < 960; q += 256) {
        int m, kc, l, xkc, col0, dcap;
        if (q < 640)      { m = 0; kc = q >> 6;          l = q & 63; xkc = 10; col0 = 0;   dcap = DL; }
        else if (q < 832) { int qq = q - 640; m = 1; kc = qq >> 6; l = qq & 63; xkc = 3; col0 = 300; dcap = DA; }
        else              { int qq = q - 832; m = 2; kc = qq >> 6; l = qq & 63; xkc = 2; col0 = 374; dcap = DV; }
        int n16 = l & 15;
        int kb = kc * 32 + (l >> 4) * 8;
        ushort_t tmp[8];
#pragma unroll
        for (int j = 0; j < 8; ++j) {
            int k = kb + j;
            tmp[j] = (k < dcap) ? f2bf(xrow[n16][col0 + k]) : (ushort_t)0;
        }
        ushort_t* dst = p.xf[m] + (((size_t)tnb * xkc + kc) * 64 + l) * 8;
        *reinterpret_cast<short8*>(dst) = *reinterpret_cast<short8*>(tmp);
    }
}

// ---------------------------------------------------------------------------
// Weight conversion into B-fragment stream order:
// wf[m] chunk id = ((zs*4 + g)*KC + kc), chunk = [lane 64][8] bf16 where
// value = W[g*256 + zs*16 + (lane&15)][kc*32 + (lane>>4)*8 + j]
// (W = [W_ih | pad | W_hh] along k). Reads are coalesced 1KB/chunk.
// ---------------------------------------------------------------------------
struct WConvP {
    const float* Wih[3];
    const float* Whh[3];
    ushort_t* wf[3];
};
__global__ __launch_bounds__(256) void wconv_kernel(WConvP p) {
    const unsigned CL = 16u * 4 * KC_L * 64;   // 73728
    const unsigned CA = 16u * 4 * KC_A * 64;   // 45056
    const unsigned CV = 16u * 4 * KC_V * 64;   // 40960
    unsigned e = blockIdx.x * 256u + threadIdx.x;
    int m, kcm, d, kp1;
    unsigned rel;
    if (e < CL)                { m = 0; rel = e;           kcm = KC_L; d = DL; kp1 = KP1_L; }
    else if (e < CL + CA)      { m = 1; rel = e - CL;      kcm = KC_A; d = DA; kp1 = KP1_A; }
    else if (e < CL + CA + CV) { m = 2; rel = e - CL - CA; kcm = KC_V; d = DV; kp1 = KP1_V; }
    else return;
    unsigned lane = rel & 63u;
    unsigned rest = rel >> 6;                  // (zs*4+g)*KC + kc
    unsigned kc = rest % (unsigned)kcm;
    unsigned zg = rest / (unsigned)kcm;
    unsigned g = zg & 3u, zs = zg >> 2;
    unsigned row = g * 256u + zs * 16u + (lane & 15u);
    unsigned kb = kc * 32u + (lane >> 4) * 8u;
    const float* __restrict__ Wih = p.Wih[m];
    const float* __restrict__ Whh = p.Whh[m];
    ushort_t tmp[8];
#pragma unroll
    for (int j = 0; j < 8; ++j) {
        int k = (int)kb + j;
        float v = 0.f;
        if (k < d) v = Wih[(size_t)row * d + k];
        else if (k >= kp1) v = Whh[(size_t)row * 256u + (k - kp1)];
        tmp[j] = f2bf(v);
    }
    *reinterpret_cast<short8*>(p.wf[m] + (size_t)rel * 8) = *reinterpret_cast<short8*>(tmp);
}

// ---------------------------------------------------------------------------
// Independent-chain LSTM: 192 blocks x 512 threads, NO inter-block sync.
// Block = (m, 64 rows); runs all 64 steps with h in a 64KB LDS double buffer
// (A-fragment layout), c in registers, weights streamed from L2 in fragment
// order (1-ahead prefetch). Each step = two z-half passes (acc stays 64 VGPR).
// Wave w, pass pp owns z in [pp*128 + w*16, +16), cf g = gate -> all 4 gates
// of each (n,z) land in-lane; pointwise fused; h written straight to LDS.
// ---------------------------------------------------------------------------
struct ChainP {
    const ushort_t* xf[3];
    const ushort_t* wf[3];
    const float* bih[3];
    const float* bhh[3];
    float* hf;   // [3][N][256] f32, written at t=63
};

template <int KP1>
__device__ __forceinline__ void chain_body(const ChainP& p, int m, int row0,
                                           ushort_t (*hb)[4][8][64][8]) {
    constexpr int KC = (KP1 + 256) / 32;
    constexpr int XKC = KP1 / 32;
    const int tid = threadIdx.x;
    const int w = tid >> 6, lane = tid & 63, ln = lane & 15, lg = lane >> 4;
    const int nb0 = row0 >> 4;
    const ushort_t* __restrict__ xf = p.xf[m];
    const ushort_t* __restrict__ wf = p.wf[m];

    // zero h buffer 0 (t=0 reads it)
    for (int e = tid; e < 8192; e += 512) ((unsigned*)hb[0])[e] = 0u;

    float bb[2][4];
#pragma unroll
    for (int pp = 0; pp < 2; ++pp) {
        int z = pp * 128 + w * 16 + ln;
        bb[pp][0] = p.bih[m][z] + p.bhh[m][z];
        bb[pp][1] = p.bih[m][256 + z] + p.bhh[m][256 + z];
        bb[pp][2] = p.bih[m][512 + z] + p.bhh[m][512 + z];
        bb[pp][3] = p.bih[m][768 + z] + p.bhh[m][768 + z];
    }
    float creg[2][4][4] = {};
    int cur = 0;
    __syncthreads();

#pragma unroll 1
    for (int t = 0; t < T_DIM; ++t) {
#pragma unroll
        for (int pp = 0; pp < 2; ++pp) {
            const int zs = pp * 8 + w;
            const ushort_t* __restrict__ wfz = wf + (size_t)zs * 4 * KC * 512;
            f32x4 acc[4][4] = {};
            short8 bcur[4];
#pragma unroll
            for (int g = 0; g < 4; ++g)
                bcur[g] = *reinterpret_cast<const short8*>(
                    wfz + ((size_t)g * KC) * 512 + lane * 8);
#pragma unroll 1
            for (int kc = 0; kc < KC; ++kc) {
                short8 bnxt[4];
                if (kc + 1 < KC) {
#pragma unroll
                    for (int g = 0; g < 4; ++g)
                        bnxt[g] = *reinterpret_cast<const short8*>(
                            wfz + ((size_t)g * KC + kc + 1) * 512 + lane * 8);
                }
                short8 a[4];
                if (kc < XKC) {
#pragma unroll
                    for (int rf = 0; rf < 4; ++rf)
                        a[rf] = *reinterpret_cast<const short8*>(
                            xf + ((((size_t)t * 256 + nb0 + rf) * XKC + kc) * 64 + lane) * 8);
                } else {
#pragma unroll
                    for (int rf = 0; rf < 4; ++rf)
                        a[rf] = *reinterpret_cast<const short8*>(&hb[cur][rf][kc - XKC][lane][0]);
                }
#pragma unroll
                for (int g = 0; g < 4; ++g)
#pragma unroll
                    for (int rf = 0; rf < 4; ++rf)
                        acc[rf][g] = __builtin_amdgcn_mfma_f32_16x16x32_bf16(
                            a[rf], bcur[g], acc[rf][g], 0, 0, 0);
                if (kc + 1 < KC) {
#pragma unroll
                    for (int g = 0; g < 4; ++g) bcur[g] = bnxt[g];
                }
            }
            // pointwise epilogue; h -> LDS next buffer (A-frag layout)
            const int z = pp * 128 + w * 16 + ln;
            const int kc2 = z >> 5;
            const int bofs = ((z >> 3) & 3) * 16;
            const int jj = z & 7;
#pragma unroll
            for (int rf = 0; rf < 4; ++rf) {
#pragma unroll
                for (int reg = 0; reg < 4; ++reg) {
                    float gi = acc[rf][0][reg] + bb[pp][0];
                    float gf = acc[rf][1][reg] + bb[pp][1];
                    float gg = acc[rf][2][reg] + bb[pp][2];
                    float go = acc[rf][3][reg] + bb[pp][3];
                    float i_ = 1.f / (1.f + __expf(-gi));
                    float f_ = 1.f / (1.f + __expf(-gf));
                    float g_ = 1.f - 2.f / (1.f + __expf(2.f * gg));
                    float o_ = 1.f / (1.f + __expf(-go));
                    float cc = f_ * creg[pp][rf][reg] + i_ * g_;
                    creg[pp][rf][reg] = cc;
                    float hh = o_ * (1.f - 2.f / (1.f + __expf(2.f * cc)));
                    hb[cur ^ 1][rf][kc2][lg * 4 + reg + bofs][jj] = f2bf(hh);
                    if (t == T_DIM - 1) {
                        int nl = rf * 16 + lg * 4 + reg;
                        p.hf[(size_t)m * N_DIM * ZD + (size_t)(row0 + nl) * ZD + z] = hh;
                    }
                }
            }
        }
        __syncthreads();   // next-buffer complete; current fully consumed
        cur ^= 1;
    }
}

__global__ __launch_bounds__(512, 2) void lstm_chain_kernel(ChainP p) {
    __shared__ ushort_t hb[2][4][8][64][8];   // 64 KB h double-buffer
    const int bid = blockIdx.x;
    const int r8 = bid & 7, idx = bid >> 3;
    const int m = idx >> 3;
    const int bm = (idx & 7) * 8 + r8;        // 0..63
    const int row0 = bm * 64;
    if (m == 0)      chain_body<KP1_L>(p, 0, row0, hb);
    else if (m == 1) chain_body<KP1_A>(p, 1, row0, hb);
    else             chain_body<KP1_V>(p, 2, row0, hb);
}

// ---------------------------------------------------------------------------
// fp32 tiled GEMM for the head layers
// ---------------------------------------------------------------------------
struct GemmP {
    const float* A1[3];
    const float* W1[3];
    const float* b1[3];
    float* C[3];
    int K1[3];
    int lda1;
    int ldc;
    int relu;
};

__device__ __forceinline__ void mac16(const float (&As)[16][64], const float (&Ws)[16][64],
                                      int tx, int ty, float (&acc)[4][4]) {
#pragma unroll
    for (int k = 0; k < 16; ++k) {
        float4 av = *reinterpret_cast<const float4*>(&As[k][ty * 4]);
        float4 bv = *reinterpret_cast<const float4*>(&Ws[k][tx * 4]);
        float a[4] = {av.x, av.y, av.z, av.w};
        float b[4] = {bv.x, bv.y, bv.z, bv.w};
#pragma unroll
        for (int i = 0; i < 4; ++i)
#pragma unroll
            for (int j = 0; j < 4; ++j)
                acc[i][j] = fmaf(a[i], b[j], acc[i][j]);
    }
}

__global__ __launch_bounds__(256) void gemm3_kernel(GemmP p) {
    const int m = blockIdx.z;
    const float* __restrict__ A1 = p.A1[m];
    const float* __restrict__ W1 = p.W1[m];
    const int K1 = p.K1[m];
    float* __restrict__ C = p.C[m];
    const int row0 = blockIdx.x * 64;
    const int col0 = blockIdx.y * 64;

    __shared__ __align__(16) float As[16][64];
    __shared__ __align__(16) float Ws[16][64];

    const int tid = threadIdx.x;
    const int tx = tid & 15, ty = tid >> 4;
    float acc[4][4] = {};

    for (int k0 = 0; k0 < K1; k0 += 16) {
#pragma unroll
        for (int i = 0; i < 4; ++i) {
            int e = tid * 4 + i;
            int rr = e >> 4, k = e & 15;
            int kk = k0 + k;
            As[k][rr] = (kk < K1) ? A1[(size_t)(row0 + rr) * p.lda1 + kk] : 0.f;
            Ws[k][rr] = (kk < K1) ? W1[(size_t)(col0 + rr) * K1 + kk] : 0.f;
        }
        __syncthreads();
        mac16(As, Ws, tx, ty, acc);
        __syncthreads();
    }

    const float* __restrict__ b1 = p.b1[m];
#pragma unroll
    for (int i = 0; i < 4; ++i) {
        int rr = row0 + ty * 4 + i;
        float v[4];
#pragma unroll
        for (int j = 0; j < 4; ++j) {
            int cc = col0 + tx * 4 + j;
            float tvl = acc[i][j] + b1[cc];
            if (p.relu) tvl = fmaxf(tvl, 0.f);
            v[j] = tvl;
        }
        float4 o = make_float4(v[0], v[1], v[2], v[3]);
        *reinterpret_cast<float4*>(&C[(size_t)rr * p.ldc + col0 + tx * 4]) = o;
    }
}

// ---------------------------------------------------------------------------
// y[n] = dot(fs[n,:384], Wy) + by
// ---------------------------------------------------------------------------
__global__ __launch_bounds__(256) void y_kernel(const float* __restrict__ fs,
                                                const float* __restrict__ Wy,
                                                const float* __restrict__ by,
                                                float* __restrict__ y) {
    unsigned wave = (blockIdx.x * 256u + threadIdx.x) >> 6;
    unsigned lane = threadIdx.x & 63u;
    if (wave >= N_DIM) return;
    const float* row = fs + (size_t)wave * 3 * FD;
    float s = 0.f;
    for (unsigned j = lane; j < 3 * FD; j += 64) s += row[j] * Wy[j];
#pragma unroll
    for (int off = 32; off; off >>= 1) s += __shfl_down(s, off);
    if (lane == 0) y[wave] = s + by[0];
}

extern "C" void kernel_launch(void* const* d_in, const int* in_sizes, int n_in,
                              void* d_out, int out_size, void* d_ws, size_t ws_size,
                              hipStream_t stream) {
    const float* x = (const float*)d_in[0];
    const float *W_ih[3], *W_hh[3], *b_ih[3], *b_hh[3], *Wfc[3], *bfc[3],
                *Wh1[3], *bh1[3], *Wh2[3], *bh2[3];
    for (int m = 0; m < 3; ++m) {
        const int b = 1 + m * 10;
        W_ih[m] = (const float*)d_in[b + 0];
        W_hh[m] = (const float*)d_in[b + 1];
        b_ih[m] = (const float*)d_in[b + 2];
        b_hh[m] = (const float*)d_in[b + 3];
        Wfc[m]  = (const float*)d_in[b + 4];
        bfc[m]  = (const float*)d_in[b + 5];
        Wh1[m]  = (const float*)d_in[b + 6];
        bh1[m]  = (const float*)d_in[b + 7];
        Wh2[m]  = (const float*)d_in[b + 8];
        bh2[m]  = (const float*)d_in[b + 9];
    }
    const float* Wy = (const float*)d_in[31];
    const float* by = (const float*)d_in[32];

    float* out   = (float*)d_out;
    float* out_l = out;
    float* out_a = out_l + (size_t)T_DIM * N_DIM * DL;
    float* out_v = out_a + (size_t)T_DIM * N_DIM * DA;
    float* out_y = out_v + (size_t)T_DIM * N_DIM * DV;

    const size_t NZ = (size_t)N_DIM * ZD;
    const size_t NF = (size_t)N_DIM * FD;
    const size_t WFL = (size_t)16 * 4 * KC_L * 512;   // ushorts
    const size_t WFA = (size_t)16 * 4 * KC_A * 512;
    const size_t WFV = (size_t)16 * 4 * KC_V * 512;

    // workspace layout
    char* wsb = (char*)d_ws;
    float* hf   = (float*)wsb;                              // 3NZ f32
    float* zbuf = hf + 3 * NZ;
    float* f1   = zbuf + 3 * NZ;
    float* fs   = f1 + 3 * NF;
    ushort_t* wf_l = (ushort_t*)(fs + 3 * NF);
    ushort_t* wf_a = wf_l + WFL;
    ushort_t* wf_v = wf_a + WFA;
    ushort_t* xf_l = wf_v + WFV;                            // T*N*320
    ushort_t* xf_a = xf_l + (size_t)T_DIM * N_DIM * KP1_L;  // T*N*96
    ushort_t* xf_v = xf_a + (size_t)T_DIM * N_DIM * KP1_A;  // T*N*64
    size_t need = (size_t)((char*)(xf_v + (size_t)T_DIM * N_DIM * KP1_V) - wsb);
    if (ws_size < need) return;

    // weight fragment conversion
    {
        WConvP p{};
        for (int m = 0; m < 3; ++m) { p.Wih[m] = W_ih[m]; p.Whh[m] = W_hh[m]; }
        p.wf[0] = wf_l; p.wf[1] = wf_a; p.wf[2] = wf_v;
        wconv_kernel<<<(16 * 4 * (KC_L + KC_A + KC_V) * 64) / 256, 256, 0, stream>>>(p);
    }

    // fused split + x fragment conversion
    {
        PrepP p{};
        p.x = x;
        p.ol = out_l; p.oa = out_a; p.ov = out_v;
        p.xf[0] = xf_l; p.xf[1] = xf_a; p.xf[2] = xf_v;
        prep_kernel<<<T_DIM * 256, 256, 0, stream>>>(p);
    }

    // independent-chain LSTM (plain launch, no grid-wide sync)
    {
        ChainP cp{};
        cp.xf[0] = xf_l; cp.xf[1] = xf_a; cp.xf[2] = xf_v;
        cp.wf[0] = wf_l; cp.wf[1] = wf_a; cp.wf[2] = wf_v;
        for (int m = 0; m < 3; ++m) { cp.bih[m] = b_ih[m]; cp.bhh[m] = b_hh[m]; }
        cp.hf = hf;
        lstm_chain_kernel<<<192, 512, 0, stream>>>(cp);
    }

    // z = h @ Wfc^T + bfc
    {
        GemmP p{};
        for (int m = 0; m < 3; ++m) {
            p.A1[m] = hf + m * NZ; p.W1[m] = Wfc[m]; p.K1[m] = ZD;
            p.b1[m] = bfc[m];      p.C[m] = zbuf + m * NZ;
        }
        p.lda1 = ZD; p.ldc = ZD; p.relu = 0;
        gemm3_kernel<<<dim3(N_DIM / 64, ZD / 64, 3), 256, 0, stream>>>(p);
    }
    // f1 = relu(z @ Wh1^T + bh1)
    {
        GemmP p{};
        for (int m = 0; m < 3; ++m) {
            p.A1[m] = zbuf + m * NZ; p.W1[m] = Wh1[m]; p.K1[m] = ZD;
            p.b1[m] = bh1[m];        p.C[m] = f1 + m * NF;
        }
        p.lda1 = ZD; p.ldc = FD; p.relu = 1;
        gemm3_kernel<<<dim3(N_DIM / 64, FD / 64, 3), 256, 0, stream>>>(p);
    }
    // fs[:, m*128:(m+1)*128] = relu(f1 @ Wh2^T + bh2)
    {
        GemmP p{};
        for (int m = 0; m < 3; ++m) {
            p.A1[m] = f1 + m * NF; p.W1[m] = Wh2[m]; p.K1[m] = FD;
            p.b1[m] = bh2[m];      p.C[m] = fs + m * FD;
        }
        p.lda1 = FD; p.ldc = 3 * FD; p.relu = 1;
        gemm3_kernel<<<dim3(N_DIM / 64, FD / 64, 3), 256, 0, stream>>>(p);
    }
    // y
    y_kernel<<<(N_DIM * 64) / 256, 256, 0, stream>>>(fs, Wy, by, out_y);
}